// Round 12
// baseline (1049.615 us; speedup 1.0000x reference)
//
#include <hip/hip_runtime.h>
#include <hip/hip_bf16.h>
#include <stdint.h>

// ---- fixed model dims ----
#define L_LAYERS 6
#define D_MODEL  1024
#define N_HEAD   16
#define H_SZ     64
#define T_SEQ    1024
#define B_BATCH  2
#define M_ROWS   2048   // B*T
#define V_VOCAB  32000

typedef __attribute__((ext_vector_type(8))) short bf16x8;
typedef __attribute__((ext_vector_type(4))) short bf16x4;
typedef __attribute__((ext_vector_type(4))) float floatx4;

static __device__ __forceinline__ short f2bf(float f) {
  __hip_bfloat16 h = __float2bfloat16(f);
  return *reinterpret_cast<short*>(&h);
}

static __device__ __forceinline__ void lds_cp16(const void* g, void* l) {
  // async global->LDS, 16B/lane; LDS dest = wave-uniform base + lane*16
  __builtin_amdgcn_global_load_lds(
      (const __attribute__((address_space(1))) uint32_t*)g,
      (__attribute__((address_space(3))) uint32_t*)l, 16, 0, 0);
}

#define WVM(n) asm volatile("s_waitcnt vmcnt(" #n ")" ::: "memory")
#define BARR __builtin_amdgcn_s_barrier()

// ---------------- weight prep: f32 [R][C] -> bf16 [C][R], batched over z ----------------
// 16B (bf16x8) output stores.
__global__ __launch_bounds__(256) void transpose_cvt(const float* __restrict__ in,
                                                     short* __restrict__ out,
                                                     int R, int C,
                                                     long in_stride, long out_stride) {
  in  += (size_t)blockIdx.z * in_stride;
  out += (size_t)blockIdx.z * out_stride;
  __shared__ float tile[64][65];
  int rt = blockIdx.x, ct = blockIdx.y;
  int tid = threadIdx.x;
  int r0 = tid >> 4;
  int c0 = (tid & 15) << 2;
  const float* ip = in + (size_t)(rt * 64) * C + ct * 64;
#pragma unroll
  for (int p = 0; p < 4; ++p) {
    int r = r0 + (p << 4);
    float4 v = *(const float4*)(ip + (size_t)r * C + c0);
    tile[r][c0] = v.x; tile[r][c0 + 1] = v.y; tile[r][c0 + 2] = v.z; tile[r][c0 + 3] = v.w;
  }
  __syncthreads();
  short* op = out + (size_t)(ct * 64) * R + rt * 64;
#pragma unroll
  for (int p = 0; p < 2; ++p) {
    int c = (tid >> 3) + (p << 5);      // 0..63 (out row = column of in-tile)
    int r8 = (tid & 7) << 3;            // 8-element chunk along R
    bf16x8 o8;
#pragma unroll
    for (int j = 0; j < 8; ++j) o8[j] = f2bf(tile[r8 + j][c]);
    *(bf16x8*)(op + (size_t)c * R + r8) = o8;
  }
}

// ---------------- fused embedding + LN1(layer0): writes x (f32) and h (bf16) ----------------
__global__ __launch_bounds__(256) void embedln_kernel(const int* __restrict__ tokens,
                                                      const float* __restrict__ tok_emb,
                                                      const float* __restrict__ pos_emb,
                                                      float* __restrict__ x,
                                                      const float* __restrict__ sc,
                                                      const float* __restrict__ bi,
                                                      short* __restrict__ out) {
  int row = blockIdx.x, tid = threadIdx.x;
  int t = row & 1023;
  int tok = tokens[row];
  int c = tid << 2;
  float4 e = *(const float4*)(tok_emb + (size_t)tok * 1024 + c);
  float4 p = *(const float4*)(pos_emb + (size_t)t * 1024 + c);
  float4 v; v.x = e.x + p.x; v.y = e.y + p.y; v.z = e.z + p.z; v.w = e.w + p.w;
  *(float4*)(x + (size_t)row * 1024 + c) = v;
  float s = v.x + v.y + v.z + v.w;
  float q = v.x * v.x + v.y * v.y + v.z * v.z + v.w * v.w;
#pragma unroll
  for (int off = 32; off > 0; off >>= 1) {
    s += __shfl_xor(s, off);
    q += __shfl_xor(q, off);
  }
  __shared__ float rs[4], rq[4];
  if ((tid & 63) == 0) { rs[tid >> 6] = s; rq[tid >> 6] = q; }
  __syncthreads();
  s = rs[0] + rs[1] + rs[2] + rs[3];
  q = rq[0] + rq[1] + rq[2] + rq[3];
  float mean = s * (1.f / 1024.f);
  float var = q * (1.f / 1024.f) - mean * mean;
  float rstd = rsqrtf(var + 1e-5f);
  float4 g = *(const float4*)(sc + c);
  float4 bb = *(const float4*)(bi + c);
  bf16x4 o4;
  o4.x = f2bf((v.x - mean) * rstd * g.x + bb.x);
  o4.y = f2bf((v.y - mean) * rstd * g.y + bb.y);
  o4.z = f2bf((v.z - mean) * rstd * g.z + bb.z);
  o4.w = f2bf((v.w - mean) * rstd * g.w + bb.w);
  *(bf16x4*)(out + (size_t)row * 1024 + c) = o4;
}

// ------ lnred: x += P0 + P1 + gbias; then LN(x) -> h (2-part split-K reduce) ------
__global__ __launch_bounds__(256) void lnred_kernel(float* __restrict__ xio,
                                                    const float* __restrict__ P0,
                                                    const float* __restrict__ P1,
                                                    const float* __restrict__ gb,
                                                    const float* __restrict__ sc,
                                                    const float* __restrict__ bi,
                                                    short* __restrict__ out) {
  int row = blockIdx.x, tid = threadIdx.x;
  int c = tid << 2;
  size_t base = (size_t)row * 1024 + c;
  float4 v = *(const float4*)(xio + base);
  float4 p0 = *(const float4*)(P0 + base);
  float4 p1 = *(const float4*)(P1 + base);
  float4 gv = *(const float4*)(gb + c);
  v.x += p0.x + p1.x + gv.x;
  v.y += p0.y + p1.y + gv.y;
  v.z += p0.z + p1.z + gv.z;
  v.w += p0.w + p1.w + gv.w;
  *(float4*)(xio + base) = v;
  float s = v.x + v.y + v.z + v.w;
  float q = v.x * v.x + v.y * v.y + v.z * v.z + v.w * v.w;
#pragma unroll
  for (int off = 32; off > 0; off >>= 1) {
    s += __shfl_xor(s, off);
    q += __shfl_xor(q, off);
  }
  __shared__ float rs[4], rq[4];
  if ((tid & 63) == 0) { rs[tid >> 6] = s; rq[tid >> 6] = q; }
  __syncthreads();
  s = rs[0] + rs[1] + rs[2] + rs[3];
  q = rq[0] + rq[1] + rq[2] + rq[3];
  float mean = s * (1.f / 1024.f);
  float var = q * (1.f / 1024.f) - mean * mean;
  float rstd = rsqrtf(var + 1e-5f);
  float4 g = *(const float4*)(sc + c);
  float4 bb = *(const float4*)(bi + c);
  bf16x4 o4;
  o4.x = f2bf((v.x - mean) * rstd * g.x + bb.x);
  o4.y = f2bf((v.y - mean) * rstd * g.y + bb.y);
  o4.z = f2bf((v.z - mean) * rstd * g.z + bb.z);
  o4.w = f2bf((v.w - mean) * rstd * g.w + bb.w);
  *(bf16x4*)(out + (size_t)row * 1024 + c) = o4;
}

// ------ lnred4: x += P01[0]+P01[1]+P23[0]+P23[1]+gbias; LN(x) -> h (4-part reduce) ------
__global__ __launch_bounds__(256) void lnred4_kernel(float* __restrict__ xio,
                                                     const float* __restrict__ P01,
                                                     const float* __restrict__ P23,
                                                     const float* __restrict__ gb,
                                                     const float* __restrict__ sc,
                                                     const float* __restrict__ bi,
                                                     short* __restrict__ out) {
  const size_t MN = (size_t)M_ROWS * 1024;
  int row = blockIdx.x, tid = threadIdx.x;
  int c = tid << 2;
  size_t base = (size_t)row * 1024 + c;
  float4 v = *(const float4*)(xio + base);
  float4 p0 = *(const float4*)(P01 + base);
  float4 p1 = *(const float4*)(P01 + MN + base);
  float4 p2 = *(const float4*)(P23 + base);
  float4 p3 = *(const float4*)(P23 + MN + base);
  float4 gv = *(const float4*)(gb + c);
  v.x += p0.x + p1.x + p2.x + p3.x + gv.x;
  v.y += p0.y + p1.y + p2.y + p3.y + gv.y;
  v.z += p0.z + p1.z + p2.z + p3.z + gv.z;
  v.w += p0.w + p1.w + p2.w + p3.w + gv.w;
  *(float4*)(xio + base) = v;
  float s = v.x + v.y + v.z + v.w;
  float q = v.x * v.x + v.y * v.y + v.z * v.z + v.w * v.w;
#pragma unroll
  for (int off = 32; off > 0; off >>= 1) {
    s += __shfl_xor(s, off);
    q += __shfl_xor(q, off);
  }
  __shared__ float rs[4], rq[4];
  if ((tid & 63) == 0) { rs[tid >> 6] = s; rq[tid >> 6] = q; }
  __syncthreads();
  s = rs[0] + rs[1] + rs[2] + rs[3];
  q = rq[0] + rq[1] + rq[2] + rq[3];
  float mean = s * (1.f / 1024.f);
  float var = q * (1.f / 1024.f) - mean * mean;
  float rstd = rsqrtf(var + 1e-5f);
  float4 g = *(const float4*)(sc + c);
  float4 bb = *(const float4*)(bi + c);
  bf16x4 o4;
  o4.x = f2bf((v.x - mean) * rstd * g.x + bb.x);
  o4.y = f2bf((v.y - mean) * rstd * g.y + bb.y);
  o4.z = f2bf((v.z - mean) * rstd * g.z + bb.z);
  o4.w = f2bf((v.w - mean) * rstd * g.w + bb.w);
  *(bf16x4*)(out + (size_t)row * 1024 + c) = o4;
}

// ------ GEMM3SK: 64x128 tile, BK=64, split-K=2, 3-buf never-drain (proven r6/r8) ------
__global__ __launch_bounds__(256) void gemm3sk_kernel(const short* __restrict__ A,
                                                      const short* __restrict__ Bt,
                                                      float* __restrict__ Pout,
                                                      int K, int N) {
  constexpr int ABY = 64 * 128;
  constexpr int BBY = 128 * 128;
  extern __shared__ char smem[];
  char* Asm = smem;
  char* Bsm = smem + 3 * ABY;
  const int NB = N >> 7;
  int nwg = 64 * NB;
  int bid = blockIdx.x;
  int wgid = (bid & 7) * (nwg >> 3) + (bid >> 3);
  int half = wgid >= (nwg >> 1);
  int w2 = wgid - half * (nwg >> 1);
  int bn = w2 >> 5, bm = w2 & 31;
  int kbase = half * (K >> 1);
  Pout += (size_t)half * M_ROWS * N;
  int tid = threadIdx.x;
  int lane = tid & 63, w = tid >> 6;
  int lr = lane & 15, lg = lane >> 4;
  int wn = w & 1, wm = w >> 1;

  const floatx4 FZ = {0.f, 0.f, 0.f, 0.f};
  floatx4 acc[2][4];
#pragma unroll
  for (int m = 0; m < 2; ++m)
#pragma unroll
    for (int n = 0; n < 4; ++n) acc[m][n] = FZ;

  size_t aoff[2], boff[4];
  {
    int rr = tid >> 3;
    int g = (tid & 7) ^ (rr & 7);
#pragma unroll
    for (int i = 0; i < 2; ++i)
      aoff[i] = (size_t)(bm * 64 + i * 32 + rr) * K + kbase + g * 8;
#pragma unroll
    for (int i = 0; i < 4; ++i)
      boff[i] = (size_t)(bn * 128 + i * 32 + rr) * K + kbase + g * 8;
  }

#define STA3(b, k0)                                                        \
  _Pragma("unroll") for (int i = 0; i < 2; ++i)                            \
    lds_cp16(A + aoff[i] + (k0), Asm + (b) * ABY + i * 4096 + tid * 16);
#define STB3(b, k0)                                                        \
  _Pragma("unroll") for (int i = 0; i < 4; ++i)                            \
    lds_cp16(Bt + boff[i] + (k0), Bsm + (b) * BBY + i * 4096 + tid * 16);
#define LDA3(b, kh)                                                        \
  _Pragma("unroll") for (int f = 0; f < 2; ++f) {                          \
    int lrow = wm * 32 + f * 16 + lr;                                      \
    af[f] = *(const bf16x8*)(Asm + (b) * ABY + lrow * 128 +                \
                             (((((kh) << 2) + lg) ^ (lrow & 7)) << 4));    \
  }
#define LDB3(b, kh)                                                        \
  _Pragma("unroll") for (int n = 0; n < 4; ++n) {                          \
    int lcol = wn * 64 + n * 16 + lr;                                      \
    bfr[n] = *(const bf16x8*)(Bsm + (b) * BBY + lcol * 128 +               \
                              (((((kh) << 2) + lg) ^ (lcol & 7)) << 4));   \
  }
#define MFMA3                                                              \
  __builtin_amdgcn_s_setprio(1);                                           \
  _Pragma("unroll") for (int f = 0; f < 2; ++f)                            \
  _Pragma("unroll") for (int n = 0; n < 4; ++n)                            \
    acc[f][n] = __builtin_amdgcn_mfma_f32_16x16x32_bf16(af[f], bfr[n],     \
                                                        acc[f][n], 0, 0, 0);\
  __builtin_amdgcn_s_setprio(0);

  const int nt = (K >> 1) >> 6;
  STA3(0, 0); STB3(0, 0);
  STA3(1, 64); STB3(1, 64);
  WVM(6);
  BARR;

  int cbuf = 0, sbuf = 2;
  for (int t = 0; t < nt; ++t) {
    bf16x8 af[2], bfr[4];
    bool pre = (t + 2 < nt);
    int k2 = (t + 2) << 6;
    if (pre) { STA3(sbuf, k2); }
    LDA3(cbuf, 0); LDB3(cbuf, 0);
    MFMA3;
    if (pre) { STB3(sbuf, k2); }
    LDA3(cbuf, 1); LDB3(cbuf, 1);
    MFMA3;
    if (pre) { WVM(6); } else { WVM(0); }
    BARR;
    cbuf = (cbuf == 2) ? 0 : cbuf + 1;
    sbuf = (sbuf == 2) ? 0 : sbuf + 1;
  }

#pragma unroll
  for (int n = 0; n < 4; ++n) {
    int col = (bn << 7) + wn * 64 + (n << 4) + lr;
#pragma unroll
    for (int m = 0; m < 2; ++m) {
      int row0 = bm * 64 + wm * 32 + (m << 4) + (lg << 2);
#pragma unroll
      for (int r = 0; r < 4; ++r)
        Pout[(size_t)(row0 + r) * N + col] = acc[m][n][r];
    }
  }
#undef STA3
#undef STB3
#undef LDA3
#undef LDB3
#undef MFMA3
}

// ------ GEMMW: 128x256 tile, 8 waves (wave 64x64), 3-buf never-drain. 144KB LDS ------
// VSPLIT: cols >=2048 (QKV's V section) written transposed to vtb, skipped in Cout.
template <bool BIAS, bool RELU, bool OUTBF16, bool VSPLIT>
__global__ __launch_bounds__(512) void gemmw_kernel(const short* __restrict__ A,
                                                    const short* __restrict__ Bt,
                                                    const float* __restrict__ bias,
                                                    void* __restrict__ Cout,
                                                    short* __restrict__ vtb,
                                                    int K, int N) {
  constexpr int ABY = 128 * 128;   // 16KB per A buf
  constexpr int BBY = 256 * 128;   // 32KB per B buf
  extern __shared__ char smem[];
  char* Asm = smem;                // 3 bufs
  char* Bsm = smem + 3 * ABY;
  const int NB = N >> 8;
  int nwg = 16 * NB;
  int bid = blockIdx.x;
  int wgid = (bid & 7) * (nwg >> 3) + (bid >> 3);
  int bn = wgid >> 4, bm = wgid & 15;               // bn-major
  int tid = threadIdx.x;
  int lane = tid & 63, w = tid >> 6;
  int lr = lane & 15, lg = lane >> 4;
  int wm = w >> 2, wn = w & 3;

  const floatx4 FZ = {0.f, 0.f, 0.f, 0.f};
  floatx4 acc[4][4];
#pragma unroll
  for (int m = 0; m < 4; ++m)
#pragma unroll
    for (int n = 0; n < 4; ++n) acc[m][n] = FZ;

  size_t aoff[2], boff[4];
  {
    int rr = tid >> 3;                               // 0..63
    int g = (tid & 7) ^ (rr & 7);
#pragma unroll
    for (int i = 0; i < 2; ++i)
      aoff[i] = (size_t)(bm * 128 + i * 64 + rr) * K + g * 8;
#pragma unroll
    for (int i = 0; i < 4; ++i)
      boff[i] = (size_t)(bn * 256 + i * 64 + rr) * K + g * 8;
  }

#define STAW(b, k0)                                                        \
  _Pragma("unroll") for (int i = 0; i < 2; ++i)                            \
    lds_cp16(A + aoff[i] + (k0), Asm + (b) * ABY + i * 8192 + tid * 16);
#define STBW(b, k0)                                                        \
  _Pragma("unroll") for (int i = 0; i < 4; ++i)                            \
    lds_cp16(Bt + boff[i] + (k0), Bsm + (b) * BBY + i * 8192 + tid * 16);
#define LDAW(b, kh)                                                        \
  _Pragma("unroll") for (int f = 0; f < 4; ++f) {                          \
    int lrow = wm * 64 + f * 16 + lr;                                      \
    af[f] = *(const bf16x8*)(Asm + (b) * ABY + lrow * 128 +                \
                             (((((kh) << 2) + lg) ^ (lrow & 7)) << 4));    \
  }
#define LDBW(b, kh)                                                        \
  _Pragma("unroll") for (int n = 0; n < 4; ++n) {                          \
    int lcol = wn * 64 + n * 16 + lr;                                      \
    bfr[n] = *(const bf16x8*)(Bsm + (b) * BBY + lcol * 128 +               \
                              (((((kh) << 2) + lg) ^ (lcol & 7)) << 4));   \
  }
#define MFMAW                                                              \
  __builtin_amdgcn_s_setprio(1);                                           \
  _Pragma("unroll") for (int f = 0; f < 4; ++f)                            \
  _Pragma("unroll") for (int n = 0; n < 4; ++n)                            \
    acc[f][n] = __builtin_amdgcn_mfma_f32_16x16x32_bf16(af[f], bfr[n],     \
                                                        acc[f][n], 0, 0, 0);\
  __builtin_amdgcn_s_setprio(0);

  const int nt = K >> 6;
  STAW(0, 0); STBW(0, 0);
  STAW(1, 64); STBW(1, 64);
  WVM(6);
  BARR;

  int cbuf = 0, sbuf = 2;
  for (int t = 0; t < nt; ++t) {
    bf16x8 af[4], bfr[4];
    bool pre = (t + 2 < nt);
    int k2 = (t + 2) << 6;
    if (pre) { STAW(sbuf, k2); }
    LDAW(cbuf, 0); LDBW(cbuf, 0);
    MFMAW;
    if (pre) { STBW(sbuf, k2); }
    LDAW(cbuf, 1); LDBW(cbuf, 1);
    MFMAW;
    if (pre) { WVM(6); } else { WVM(0); }
    BARR;
    cbuf = (cbuf == 2) ? 0 : cbuf + 1;
    sbuf = (sbuf == 2) ? 0 : sbuf + 1;
  }

#pragma unroll
  for (int n = 0; n < 4; ++n) {
    int col = (bn << 8) + wn * 64 + (n << 4) + lr;
    float bv = 0.f;
    if (BIAS) bv = bias[col];
#pragma unroll
    for (int m = 0; m < 4; ++m) {
      int row0 = bm * 128 + wm * 64 + (m << 4) + (lg << 2);
      if (VSPLIT && col >= 2048) {
        // V section: write transposed to vtb[b*16+head][hs][t], 4 consecutive t
        int hc = col - 2048;
        int brow = row0 >> 10, t0 = row0 & 1023;
        ushort4 pk;
        pk.x = (unsigned short)f2bf(acc[m][n][0]);
        pk.y = (unsigned short)f2bf(acc[m][n][1]);
        pk.z = (unsigned short)f2bf(acc[m][n][2]);
        pk.w = (unsigned short)f2bf(acc[m][n][3]);
        *(ushort4*)(vtb + ((size_t)(((brow << 4) + (hc >> 6)) << 6) + (hc & 63)) * 1024 + t0) = pk;
      } else {
#pragma unroll
        for (int r = 0; r < 4; ++r) {
          size_t idx = (size_t)(row0 + r) * N + col;
          float val = acc[m][n][r] + bv;
          if (RELU) val = fmaxf(val, 0.f);
          if (OUTBF16) ((short*)Cout)[idx] = f2bf(val);
          else ((float*)Cout)[idx] = val;
        }
      }
    }
  }
#undef STAW
#undef STBW
#undef LDAW
#undef LDBW
#undef MFMAW
}

// ------ GEMMWSK: gemmw with split-K=4, f32 partials (parts 0,1->P01; 2,3->P23) ------
__global__ __launch_bounds__(512) void gemmwsk_kernel(const short* __restrict__ A,
                                                      const short* __restrict__ Bt,
                                                      float* __restrict__ P01,
                                                      float* __restrict__ P23,
                                                      int K, int N) {
  constexpr int ABY = 128 * 128;
  constexpr int BBY = 256 * 128;
  extern __shared__ char smem[];
  char* Asm = smem;
  char* Bsm = smem + 3 * ABY;
  const int NB = N >> 8;
  int nwg = 16 * NB * 4;
  int bid = blockIdx.x;
  int wgid = (bid & 7) * (nwg >> 3) + (bid >> 3);
  int per = nwg >> 2;
  int part = wgid / per;
  int w2 = wgid - part * per;
  int bn = w2 >> 4, bm = w2 & 15;
  int kbase = part * (K >> 2);
  float* Pout = (part < 2 ? P01 + (size_t)part * M_ROWS * N
                          : P23 + (size_t)(part - 2) * M_ROWS * N);
  int tid = threadIdx.x;
  int lane = tid & 63, w = tid >> 6;
  int lr = lane & 15, lg = lane >> 4;
  int wm = w >> 2, wn = w & 3;

  const floatx4 FZ = {0.f, 0.f, 0.f, 0.f};
  floatx4 acc[4][4];
#pragma unroll
  for (int m = 0; m < 4; ++m)
#pragma unroll
    for (int n = 0; n < 4; ++n) acc[m][n] = FZ;

  size_t aoff[2], boff[4];
  {
    int rr = tid >> 3;
    int g = (tid & 7) ^ (rr & 7);
#pragma unroll
    for (int i = 0; i < 2; ++i)
      aoff[i] = (size_t)(bm * 128 + i * 64 + rr) * K + kbase + g * 8;
#pragma unroll
    for (int i = 0; i < 4; ++i)
      boff[i] = (size_t)(bn * 256 + i * 64 + rr) * K + kbase + g * 8;
  }

#define STAW(b, k0)                                                        \
  _Pragma("unroll") for (int i = 0; i < 2; ++i)                            \
    lds_cp16(A + aoff[i] + (k0), Asm + (b) * ABY + i * 8192 + tid * 16);
#define STBW(b, k0)                                                        \
  _Pragma("unroll") for (int i = 0; i < 4; ++i)                            \
    lds_cp16(Bt + boff[i] + (k0), Bsm + (b) * BBY + i * 8192 + tid * 16);
#define LDAW(b, kh)                                                        \
  _Pragma("unroll") for (int f = 0; f < 4; ++f) {                          \
    int lrow = wm * 64 + f * 16 + lr;                                      \
    af[f] = *(const bf16x8*)(Asm + (b) * ABY + lrow * 128 +                \
                             (((((kh) << 2) + lg) ^ (lrow & 7)) << 4));    \
  }
#define LDBW(b, kh)                                                        \
  _Pragma("unroll") for (int n = 0; n < 4; ++n) {                          \
    int lcol = wn * 64 + n * 16 + lr;                                      \
    bfr[n] = *(const bf16x8*)(Bsm + (b) * BBY + lcol * 128 +               \
                              (((((kh) << 2) + lg) ^ (lcol & 7)) << 4));   \
  }
#define MFMAW                                                              \
  __builtin_amdgcn_s_setprio(1);                                           \
  _Pragma("unroll") for (int f = 0; f < 4; ++f)                            \
  _Pragma("unroll") for (int n = 0; n < 4; ++n)                            \
    acc[f][n] = __builtin_amdgcn_mfma_f32_16x16x32_bf16(af[f], bfr[n],     \
                                                        acc[f][n], 0, 0, 0);\
  __builtin_amdgcn_s_setprio(0);

  const int nt = (K >> 2) >> 6;
  STAW(0, 0); STBW(0, 0);
  STAW(1, 64); STBW(1, 64);
  WVM(6);
  BARR;

  int cbuf = 0, sbuf = 2;
  for (int t = 0; t < nt; ++t) {
    bf16x8 af[4], bfr[4];
    bool pre = (t + 2 < nt);
    int k2 = (t + 2) << 6;
    if (pre) { STAW(sbuf, k2); }
    LDAW(cbuf, 0); LDBW(cbuf, 0);
    MFMAW;
    if (pre) { STBW(sbuf, k2); }
    LDAW(cbuf, 1); LDBW(cbuf, 1);
    MFMAW;
    if (pre) { WVM(6); } else { WVM(0); }
    BARR;
    cbuf = (cbuf == 2) ? 0 : cbuf + 1;
    sbuf = (sbuf == 2) ? 0 : sbuf + 1;
  }

#pragma unroll
  for (int n = 0; n < 4; ++n) {
    int col = (bn << 8) + wn * 64 + (n << 4) + lr;
#pragma unroll
    for (int m = 0; m < 4; ++m) {
      int row0 = bm * 128 + wm * 64 + (m << 4) + (lg << 2);
#pragma unroll
      for (int r = 0; r < 4; ++r)
        Pout[(size_t)(row0 + r) * N + col] = acc[m][n][r];
    }
  }
#undef STAW
#undef STBW
#undef LDAW
#undef LDBW
#undef MFMAW
}

// ---------------- GEMM8: 256x256 8-phase, dynamic LDS 128KB (LM head) ----------------
template <bool BIAS, bool OUTBF16>
__global__ __launch_bounds__(512) void gemm8_kernel(const short* __restrict__ A,
                                                    const short* __restrict__ Bt,
                                                    const float* __restrict__ bias,
                                                    void* __restrict__ Cout,
                                                    int K, int N) {
  extern __shared__ char smem[];
  char* Asm = smem;            // [buf][chunk][128 rows][128B]
  char* Bsm = smem + 65536;    // [buf][256 cols][128B]
  const int NB = N >> 8;
  int nwg = 8 * NB;
  int bid = blockIdx.x;
  int wgid = (bid & 7) * (nwg >> 3) + (bid >> 3);
  int bm = wgid & 7, bn = wgid >> 3;
  int tid = threadIdx.x;
  int lane = tid & 63, w = tid >> 6;
  int lr = lane & 15, lg = lane >> 4;
  int wm = w >> 2, wn = w & 3;

  const floatx4 FZ = {0.f, 0.f, 0.f, 0.f};
  floatx4 acc[8][4];
#pragma unroll
  for (int m = 0; m < 8; ++m)
#pragma unroll
    for (int n = 0; n < 4; ++n) acc[m][n] = FZ;

  size_t aoff[2][2], boff[4];
  {
    int rr = tid >> 3;
    int g = (tid & 7) ^ (rr & 7);
#pragma unroll
    for (int c = 0; c < 2; ++c)
#pragma unroll
      for (int i = 0; i < 2; ++i) {
        int lrow = i * 64 + rr;
        int grow = (lrow & 63) + ((lrow >> 6) << 7) + (c << 6);
        aoff[c][i] = (size_t)(bm * 256 + grow) * K + g * 8;
      }
#pragma unroll
    for (int i = 0; i < 4; ++i)
      boff[i] = (size_t)(bn * 256 + i * 64 + rr) * K + g * 8;
  }

  bf16x8 areg[4], breg[2][4];

#define LDA8(chunk, kh)                                                          \
  _Pragma("unroll") for (int f = 0; f < 4; ++f) {                                \
    int lrow = wm * 64 + f * 16 + lr;                                            \
    areg[f] = *(const bf16x8*)(Asm + buf * 32768 + (chunk) * 16384 + lrow * 128  \
                               + (((((kh) << 2) + lg) ^ (lrow & 7)) << 4));      \
  }
#define LDB8(kh)                                                                 \
  _Pragma("unroll") for (int n = 0; n < 4; ++n) {                                \
    int lcol = wn * 64 + n * 16 + lr;                                            \
    breg[kh][n] = *(const bf16x8*)(Bsm + buf * 32768 + lcol * 128                \
                                   + (((((kh) << 2) + lg) ^ (lcol & 7)) << 4));  \
  }
#define MFMA16(mh, kh)                                                           \
  __builtin_amdgcn_s_setprio(1);                                                 \
  _Pragma("unroll") for (int f = 0; f < 4; ++f)                                  \
  _Pragma("unroll") for (int n = 0; n < 4; ++n)                                  \
    acc[(mh) * 4 + f][n] = __builtin_amdgcn_mfma_f32_16x16x32_bf16(              \
        areg[f], breg[kh][n], acc[(mh) * 4 + f][n], 0, 0, 0);                    \
  __builtin_amdgcn_s_setprio(0);
#define STA8(chunk, dstbuf, k0)                                                  \
  _Pragma("unroll") for (int i = 0; i < 2; ++i)                                  \
    lds_cp16(A + aoff[chunk][i] + (k0),                                          \
             Asm + (dstbuf) * 32768 + (chunk) * 16384 + i * 8192 + tid * 16);
#define STB8(dstbuf, k0)                                                         \
  _Pragma("unroll") for (int i = 0; i < 4; ++i)                                  \
    lds_cp16(Bt + boff[i] + (k0),                                                \
             Bsm + (dstbuf) * 32768 + i * 8192 + tid * 16);

  const int nt = K >> 6;
  STA8(0, 0, 0); STB8(0, 0); STA8(1, 0, 0);
  WVM(2);
  BARR;

  int buf = 0;
  for (int t = 0; t < nt - 1; ++t) {
    int k1 = (t + 1) << 6;
    int ob = buf ^ 1;
    LDA8(0, 0); LDB8(0);
    STA8(0, ob, k1);
    BARR;
    MFMA16(0, 0);
    BARR;
    LDA8(0, 1); LDB8(1);
    STB8(ob, k1);
    WVM(6);
    BARR;
    MFMA16(0, 1);
    BARR;
    LDA8(1, 0);
    STA8(1, ob, k1);
    BARR;
    MFMA16(1, 0);
    BARR;
    LDA8(1, 1);
    WVM(2);
    BARR;
    MFMA16(1, 1);
    BARR;
    buf ^= 1;
  }
  LDA8(0, 0); LDB8(0);
  MFMA16(0, 0);
  LDA8(0, 1); LDB8(1);
  MFMA16(0, 1);
  WVM(0);
  BARR;
  LDA8(1, 0);
  MFMA16(1, 0);
  LDA8(1, 1);
  MFMA16(1, 1);

#pragma unroll
  for (int n = 0; n < 4; ++n) {
    int col = (bn << 8) + (wn << 6) + (n << 4) + lr;
    float bv = 0.f;
    if (BIAS) bv = bias[col];
#pragma unroll
    for (int m = 0; m < 8; ++m) {
      int row0 = (bm << 8) + (wm << 7) + (m << 4) + (lg << 2);
#pragma unroll
      for (int r = 0; r < 4; ++r) {
        size_t idx = (size_t)(row0 + r) * N + col;
        float val = acc[m][n][r] + bv;
        if (OUTBF16) ((short*)Cout)[idx] = f2bf(val);
        else ((float*)Cout)[idx] = val;
      }
    }
  }
#undef LDA8
#undef LDB8
#undef MFMA16
#undef STA8
#undef STB8
}

// ---------------- flash attention: KVBLK=128, mask-free main loop + trimmed epilogue ----------------
__global__ __launch_bounds__(256) void attn_kernel(const short* __restrict__ qkv,
                                                   const short* __restrict__ vt,
                                                   short* __restrict__ out) {
  int bh = blockIdx.x;
  int qt = blockIdx.y;
  int b = bh >> 4, hh = bh & 15;
  int tid = threadIdx.x;
  int lane = tid & 63, w = tid >> 6;
  int lr = lane & 15, lg = lane >> 4;

  __shared__ short Ks[128 * 64];    // [kv][hs], 128B rows, granule ^= row&7
  __shared__ short Vs[64 * 128];    // V^T [hs][kv], 256B rows, granule ^= row&15
  __shared__ short Ps[4][16 * 132]; // per-wave P strip [16 q][132 kv-stride]

  const floatx4 FZ = {0.f, 0.f, 0.f, 0.f};
  const float C2 = 0.18033688f;     // HS^-0.5 * log2(e)
  const short* qb = qkv + (size_t)((b << 10) + (qt << 6) + (w << 4) + lr) * 3072 + (hh << 6);
  bf16x8 qf0 = *(const bf16x8*)(qb + (lg << 3));
  bf16x8 qf1 = *(const bf16x8*)(qb + 32 + (lg << 3));

  floatx4 o[4];
  float mrun[4], lrun[4];
#pragma unroll
  for (int r = 0; r < 4; ++r) { o[r] = FZ; mrun[r] = -3e38f; lrun[r] = 0.f; }

  int krow = tid >> 3, kgr = tid & 7;     // K staging: 32 rows/inst
  int vrow = tid >> 4, vgr = tid & 15;    // V staging: 16 rows/inst
  const short* kB = qkv + (size_t)(b << 10) * 3072 + 1024 + (hh << 6);
  const short* vB = vt + (size_t)(bh << 6) * 1024;

#define STKV(JT)                                                           \
  _Pragma("unroll") for (int i = 0; i < 4; ++i) {                          \
    int r = (i << 5) + krow;                                               \
    lds_cp16(kB + (size_t)(((JT) << 7) + r) * 3072 + ((kgr ^ (r & 7)) << 3), \
             (char*)Ks + i * 4096 + tid * 16);                             \
  }                                                                        \
  _Pragma("unroll") for (int i = 0; i < 4; ++i) {                          \
    int r = (i << 4) + vrow;                                               \
    lds_cp16(vB + (size_t)r * 1024 + ((JT) << 7) + ((vgr ^ (r & 15)) << 3), \
             (char*)Vs + i * 4096 + tid * 16);                             \
  }

#define CHUNK_COMPUTE(NF, MASK, JT)                                        \
  {                                                                        \
    const char* KsB = (const char*)Ks;                                     \
    const char* VsB = (const char*)Vs;                                     \
    floatx4 s[NF];                                                         \
    _Pragma("unroll") for (int f = 0; f < NF; ++f) {                       \
      int rk = (f << 4) + lr;                                              \
      int sw = rk & 7;                                                     \
      bf16x8 kf0 = *(const bf16x8*)(KsB + rk * 128 + ((lg ^ sw) << 4));    \
      bf16x8 kf1 = *(const bf16x8*)(KsB + rk * 128 + (((4 + lg) ^ sw) << 4)); \
      floatx4 t0 = __builtin_amdgcn_mfma_f32_16x16x32_bf16(qf0, kf0, FZ, 0, 0, 0); \
      s[f] = __builtin_amdgcn_mfma_f32_16x16x32_bf16(qf1, kf1, t0, 0, 0, 0); \
    }                                                                      \
    int qrow0 = (qt << 6) + (w << 4) + (lg << 2);                          \
    _Pragma("unroll") for (int f = 0; f < NF; ++f)                         \
    _Pragma("unroll") for (int r = 0; r < 4; ++r) {                        \
      float sv = s[f][r] * C2;                                             \
      if (MASK && (((JT) << 7) + (f << 4) + lr > qrow0 + r)) sv = -3e38f;  \
      s[f][r] = sv;                                                        \
    }                                                                      \
    float mt[4] = {-3e38f, -3e38f, -3e38f, -3e38f};                        \
    _Pragma("unroll") for (int f = 0; f < NF; ++f)                         \
    _Pragma("unroll") for (int r = 0; r < 4; ++r) mt[r] = fmaxf(mt[r], s[f][r]); \
    _Pragma("unroll") for (int off = 1; off < 16; off <<= 1)               \
    _Pragma("unroll") for (int r = 0; r < 4; ++r)                          \
      mt[r] = fmaxf(mt[r], __shfl_xor(mt[r], off));                        \
    float corr[4], psum[4];                                                \
    _Pragma("unroll") for (int r = 0; r < 4; ++r) {                        \
      float mnew = fmaxf(mrun[r], mt[r]);                                  \
      corr[r] = exp2f(mrun[r] - mnew);                                     \
      mrun[r] = mnew;                                                      \
      float ps = 0.f;                                                      \
      _Pragma("unroll") for (int f = 0; f < NF; ++f) {                     \
        float e = exp2f(s[f][r] - mnew);                                   \
        s[f][r] = e;                                                       \
        ps += e;                                                           \
      }                                                                    \
      psum[r] = ps;                                                        \
    }                                                                      \
    _Pragma("unroll") for (int off = 1; off < 16; off <<= 1)               \
    _Pragma("unroll") for (int r = 0; r < 4; ++r)                          \
      psum[r] += __shfl_xor(psum[r], off);                                 \
    floatx4 cv;                                                            \
    _Pragma("unroll") for (int r = 0; r < 4; ++r) {                        \
      lrun[r] = lrun[r] * corr[r] + psum[r];                               \
      cv[r] = corr[r];                                                     \
    }                                                                      \
    _Pragma("unroll") for (int f = 0; f < 4; ++f) o[f] *= cv;              \
    char* PsB = (char*)&Ps[w][0];                                          \
    _Pragma("unroll") for (int f = 0; f < NF; ++f)                         \
    _Pragma("unroll") for (int r = 0; r < 4; ++r)                          \
      *(short*)(PsB + ((lg << 2) + r) * 264 + (((f << 4) + lr) << 1)) =    \
          f2bf(s[f][r]);                                                   \
    _Pragma("unroll") for (int kk = 0; kk < (NF >> 1); ++kk) {             \
      const char* pb = PsB + lr * 264 + (kk << 6) + (lg << 4);             \
      union { struct { bf16x4 lo, hi; } h2; bf16x8 v; } pu;                \
      pu.h2.lo = *(const bf16x4*)pb;                                       \
      pu.h2.hi = *(const bf16x4*)(pb + 8);                                 \
      bf16x8 pa = pu.v;                                                    \
      _Pragma("unroll") for (int f = 0; f < 4; ++f) {                      \
        int rv = (f << 4) + lr;                                            \
        bf16x8 vf = *(const bf16x8*)(VsB + rv * 256 +                      \
                                     ((((kk << 2) + lg) ^ (rv & 15)) << 4)); \
        o[f] = __builtin_amdgcn_mfma_f32_16x16x32_bf16(pa, vf, o[f], 0, 0, 0); \
      }                                                                    \
    }                                                                      \
  }

  const int nfull = qt >> 1;              // chunks with no masking at all
  for (int jt = 0; jt < nfull; ++jt) {
    STKV(jt);
    WVM(0);
    BARR;
    CHUNK_COMPUTE(8, false, jt)
    BARR;                                 // close reads before next staging
  }
  // epilogue chunk (block-uniform branch on qt parity)
  STKV(nfull);
  WVM(0);
  BARR;
  if (qt & 1) {
    CHUNK_COMPUTE(8, true, nfull)
  } else {
    CHUNK_COMPUTE(4, true, nfull)         // upper 64 kv fully masked -> skip
  }
#undef STKV
#undef CHUNK_COMPUTE

#pragma unroll
  for (int f = 0; f < 4; ++f) {
#pragma unroll
    for (int r = 0; r < 4; ++r) {
      int row = (qt << 6) + (w << 4) + (lg << 2) + r;
      int col = (hh << 6) + (f << 4) + lr;
      out[(size_t)((b << 10) + row) * 1024 + col] = f2bf(o[f][r] / lrun[r]);
    }
  }
}

// ---------------- launch ----------------
extern "C" void kernel_launch(void* const* d_in, const int* in_sizes, int n_in,
                              void* d_out, int out_size, void* d_ws, size_t ws_size,
                              hipStream_t stream) {
  const int*   tokens  = (const int*)d_in[0];
  const float* tok_emb = (const float*)d_in[1];
  const float* pos_emb = (const float*)d_in[2];
  const float* Wq  = (const float*)d_in[3];
  const float* Wk  = (const float*)d_in[4];
  const float* Wv  = (const float*)d_in[5];
  const float* Wo  = (const float*)d_in[6];
  const float* bo  = (const float*)d_in[7];
  const float* ln1s = (const float*)d_in[8];
  const float* ln1b = (const float*)d_in[9];
  const float* ln2s = (const float*)d_in[10];
  const float* ln2b = (const float*)d_in[11];
  const float* W1  = (const float*)d_in[12];
  const float* b1  = (const float*)d_in[13];
  const float* W2  = (const float*)d_in[14];
  const float* b2  = (const float*)d_in[15];
  const float* lnfs = (const float*)d_in[16];
  const float* lnfb = (const float*)d_in[17];
  const float* Wlm = (const float*)d_in[18];
  const float* blm = (const float*)d_in[19];

  short* wqkvT = (short*)d_ws;                               // [L][3072][1024]
  short* woT   = wqkvT + (size_t)L_LAYERS * 3072 * 1024;     // [L][1024][1024]
  short* w1T   = woT   + (size_t)L_LAYERS * 1024 * 1024;     // [L][4096][1024]
  short* w2T   = w1T   + (size_t)L_LAYERS * 4096 * 1024;     // [L][1024][4096]
  short* wlmT  = w2T   + (size_t)L_LAYERS * 1024 * 4096;     // [32000][1024]
  float* x     = (float*)(wlmT + (size_t)V_VOCAB * 1024);    // [2048][1024] f32
  short* h     = (short*)(x + (size_t)M_ROWS * 1024);        // [2048][1024] bf16
  short* qkv   = h + (size_t)M_ROWS * 1024;                  // [2048][3072] bf16
  short* vtb   = qkv + (size_t)M_ROWS * 3072;                // [32][64][1024] bf16
  short* attnb = vtb + (size_t)B_BATCH * N_HEAD * H_SZ * T_SEQ; // [2048][1024]
  short* mid   = attnb + (size_t)M_ROWS * 1024;              // [2048][4096] bf16
  float* psum  = (float*)(mid + (size_t)M_ROWS * 4096);      // 2x[2048][1024] f32
  float* psum1 = psum + (size_t)M_ROWS * 1024;
  // split-K parts 2,3 reuse the dead qkv+vtb region (16MB fits in 16.6MB)
  float* psum23 = (float*)qkv;

  dim3 blk(256, 1, 1);

  // raise dynamic-LDS caps (idempotent, host-side, capture-safe)
  (void)hipFuncSetAttribute(reinterpret_cast<const void*>(&gemm8_kernel<true, false>),
                            hipFuncAttributeMaxDynamicSharedMemorySize, 131072);
  (void)hipFuncSetAttribute(reinterpret_cast<const void*>(&gemm3sk_kernel),
                            hipFuncAttributeMaxDynamicSharedMemorySize, 73728);
  (void)hipFuncSetAttribute(reinterpret_cast<const void*>(&gemmw_kernel<false, false, true, true>),
                            hipFuncAttributeMaxDynamicSharedMemorySize, 147456);
  (void)hipFuncSetAttribute(reinterpret_cast<const void*>(&gemmw_kernel<true, true, true, false>),
                            hipFuncAttributeMaxDynamicSharedMemorySize, 147456);
  (void)hipFuncSetAttribute(reinterpret_cast<const void*>(&gemmwsk_kernel),
                            hipFuncAttributeMaxDynamicSharedMemorySize, 147456);

  // ---- weight prep ----
  transpose_cvt<<<dim3(16, 16, 6), blk, 0, stream>>>(Wq, wqkvT,             1024, 1024, 1048576, 3072 * 1024);
  transpose_cvt<<<dim3(16, 16, 6), blk, 0, stream>>>(Wk, wqkvT + 1048576,   1024, 1024, 1048576, 3072 * 1024);
  transpose_cvt<<<dim3(16, 16, 6), blk, 0, stream>>>(Wv, wqkvT + 2097152,   1024, 1024, 1048576, 3072 * 1024);
  transpose_cvt<<<dim3(16, 16, 6), blk, 0, stream>>>(Wo, woT,               1024, 1024, 1048576, 1048576);
  transpose_cvt<<<dim3(16, 64, 6), blk, 0, stream>>>(W1, w1T,               1024, 4096, 4194304, 4194304);
  transpose_cvt<<<dim3(64, 16, 6), blk, 0, stream>>>(W2, w2T,               4096, 1024, 4194304, 4194304);
  transpose_cvt<<<dim3(16, 500, 1), blk, 0, stream>>>(Wlm, wlmT,            1024, V_VOCAB, 0, 0);

  // ---- forward ----
  embedln_kernel<<<M_ROWS, blk, 0, stream>>>(tokens, tok_emb, pos_emb, x, ln1s, ln1b, h);

  for (int l = 0; l < L_LAYERS; ++l) {
    if (l > 0) {
      // fused: x += 4 mlp2 partials + b2[l-1]; h = LN1_l(x)
      lnred4_kernel<<<M_ROWS, blk, 0, stream>>>(x, psum, psum23, b2 + (l - 1) * 1024,
                                                ln1s + l * 1024, ln1b + l * 1024, h);
    }
    // QKV: 128x256-tile 8-wave; V section written transposed to vtb (VSPLIT)
    gemmw_kernel<false, false, true, true><<<16 * 12, dim3(512, 1, 1), 147456, stream>>>(
        h, wqkvT + (size_t)l * 3072 * 1024, nullptr, qkv, vtb, 1024, 3072);
    attn_kernel<<<dim3(32, 16), blk, 0, stream>>>(qkv, vtb, attnb);
    // proj split-K=2 -> partials (512 blocks, nt=8)
    gemm3sk_kernel<<<64 * 8, blk, 73728, stream>>>(
        attnb, woT + (size_t)l * 1048576, psum, 1024, 1024);
    // fused: x += proj partials + bo[l]; h = LN2_l(x)
    lnred_kernel<<<M_ROWS, blk, 0, stream>>>(x, psum, psum1, bo + l * 1024,
                                             ln2s + l * 1024, ln2b + l * 1024, h);
    // MLP1: 128x256-tile 8-wave (grid 256)
    gemmw_kernel<true, true, true, false><<<16 * 16, dim3(512, 1, 1), 147456, stream>>>(
        h, w1T + (size_t)l * 4194304, b1 + l * 4096, mid, nullptr, 1024, 4096);
    // MLP2 split-K=4 -> partials (parts 2,3 over dead qkv buffer; nt=16)
    gemmwsk_kernel<<<16 * 16, dim3(512, 1, 1), 147456, stream>>>(
        mid, w2T + (size_t)l * 4194304, psum, psum23, 4096, 1024);
  }

  // fused final: x += 4 mlp2 partials + b2[5]; h = LNf(x)
  lnred4_kernel<<<M_ROWS, blk, 0, stream>>>(x, psum, psum23, b2 + 5 * 1024,
                                            lnfs, lnfb, h);
  gemm8_kernel<true, false><<<dim3(8 * 125), dim3(512, 1, 1), 131072, stream>>>(
      h, wlmT, blm, (float*)d_out, 1024, V_VOCAB);
}

// Round 13
// 1006.230 us; speedup vs baseline: 1.0431x; 1.0431x over previous
//
#include <hip/hip_runtime.h>
#include <hip/hip_bf16.h>
#include <stdint.h>

// ---- fixed model dims ----
#define L_LAYERS 6
#define D_MODEL  1024
#define N_HEAD   16
#define H_SZ     64
#define T_SEQ    1024
#define B_BATCH  2
#define M_ROWS   2048   // B*T
#define V_VOCAB  32000

typedef __attribute__((ext_vector_type(8))) short bf16x8;
typedef __attribute__((ext_vector_type(4))) short bf16x4;
typedef __attribute__((ext_vector_type(4))) float floatx4;

static __device__ __forceinline__ short f2bf(float f) {
  __hip_bfloat16 h = __float2bfloat16(f);
  return *reinterpret_cast<short*>(&h);
}
static __device__ __forceinline__ float bf2f(short s) {
  unsigned u = ((unsigned)(unsigned short)s) << 16;
  return *reinterpret_cast<float*>(&u);
}

static __device__ __forceinline__ void lds_cp16(const void* g, void* l) {
  // async global->LDS, 16B/lane; LDS dest = wave-uniform base + lane*16
  __builtin_amdgcn_global_load_lds(
      (const __attribute__((address_space(1))) uint32_t*)g,
      (__attribute__((address_space(3))) uint32_t*)l, 16, 0, 0);
}

#define WVM(n) asm volatile("s_waitcnt vmcnt(" #n ")" ::: "memory")
#define BARR __builtin_amdgcn_s_barrier()

// ---------------- weight prep: f32 [R][C] -> bf16 [C][R], batched over z ----------------
__global__ __launch_bounds__(256) void transpose_cvt(const float* __restrict__ in,
                                                     short* __restrict__ out,
                                                     int R, int C,
                                                     long in_stride, long out_stride) {
  in  += (size_t)blockIdx.z * in_stride;
  out += (size_t)blockIdx.z * out_stride;
  __shared__ float tile[64][65];
  int rt = blockIdx.x, ct = blockIdx.y;
  int tid = threadIdx.x;
  int r0 = tid >> 4;
  int c0 = (tid & 15) << 2;
  const float* ip = in + (size_t)(rt * 64) * C + ct * 64;
#pragma unroll
  for (int p = 0; p < 4; ++p) {
    int r = r0 + (p << 4);
    float4 v = *(const float4*)(ip + (size_t)r * C + c0);
    tile[r][c0] = v.x; tile[r][c0 + 1] = v.y; tile[r][c0 + 2] = v.z; tile[r][c0 + 3] = v.w;
  }
  __syncthreads();
  short* op = out + (size_t)(ct * 64) * R + rt * 64;
#pragma unroll
  for (int p = 0; p < 2; ++p) {
    int c = (tid >> 3) + (p << 5);      // 0..63 (out row = column of in-tile)
    int r8 = (tid & 7) << 3;            // 8-element chunk along R
    bf16x8 o8;
#pragma unroll
    for (int j = 0; j < 8; ++j) o8[j] = f2bf(tile[r8 + j][c]);
    *(bf16x8*)(op + (size_t)c * R + r8) = o8;
  }
}

// ---------------- fused embedding + LN1(layer0): writes x (f32) and h (bf16) ----------------
__global__ __launch_bounds__(256) void embedln_kernel(const int* __restrict__ tokens,
                                                      const float* __restrict__ tok_emb,
                                                      const float* __restrict__ pos_emb,
                                                      float* __restrict__ x,
                                                      const float* __restrict__ sc,
                                                      const float* __restrict__ bi,
                                                      short* __restrict__ out) {
  int row = blockIdx.x, tid = threadIdx.x;
  int t = row & 1023;
  int tok = tokens[row];
  int c = tid << 2;
  float4 e = *(const float4*)(tok_emb + (size_t)tok * 1024 + c);
  float4 p = *(const float4*)(pos_emb + (size_t)t * 1024 + c);
  float4 v; v.x = e.x + p.x; v.y = e.y + p.y; v.z = e.z + p.z; v.w = e.w + p.w;
  *(float4*)(x + (size_t)row * 1024 + c) = v;
  float s = v.x + v.y + v.z + v.w;
  float q = v.x * v.x + v.y * v.y + v.z * v.z + v.w * v.w;
#pragma unroll
  for (int off = 32; off > 0; off >>= 1) {
    s += __shfl_xor(s, off);
    q += __shfl_xor(q, off);
  }
  __shared__ float rs[4], rq[4];
  if ((tid & 63) == 0) { rs[tid >> 6] = s; rq[tid >> 6] = q; }
  __syncthreads();
  s = rs[0] + rs[1] + rs[2] + rs[3];
  q = rq[0] + rq[1] + rq[2] + rq[3];
  float mean = s * (1.f / 1024.f);
  float var = q * (1.f / 1024.f) - mean * mean;
  float rstd = rsqrtf(var + 1e-5f);
  float4 g = *(const float4*)(sc + c);
  float4 bb = *(const float4*)(bi + c);
  bf16x4 o4;
  o4.x = f2bf((v.x - mean) * rstd * g.x + bb.x);
  o4.y = f2bf((v.y - mean) * rstd * g.y + bb.y);
  o4.z = f2bf((v.z - mean) * rstd * g.z + bb.z);
  o4.w = f2bf((v.w - mean) * rstd * g.w + bb.w);
  *(bf16x4*)(out + (size_t)row * 1024 + c) = o4;
}

// ------ lnred: x += P0 + P1 + gbias; then LN(x) -> h  (bf16 partials) ------
__global__ __launch_bounds__(256) void lnred_kernel(float* __restrict__ xio,
                                                    const short* __restrict__ P0,
                                                    const short* __restrict__ P1,
                                                    const float* __restrict__ gb,
                                                    const float* __restrict__ sc,
                                                    const float* __restrict__ bi,
                                                    short* __restrict__ out) {
  int row = blockIdx.x, tid = threadIdx.x;
  int c = tid << 2;
  size_t base = (size_t)row * 1024 + c;
  float4 v = *(const float4*)(xio + base);
  bf16x4 p0 = *(const bf16x4*)(P0 + base);
  bf16x4 p1 = *(const bf16x4*)(P1 + base);
  float4 gv = *(const float4*)(gb + c);
  v.x += bf2f(p0.x) + bf2f(p1.x) + gv.x;
  v.y += bf2f(p0.y) + bf2f(p1.y) + gv.y;
  v.z += bf2f(p0.z) + bf2f(p1.z) + gv.z;
  v.w += bf2f(p0.w) + bf2f(p1.w) + gv.w;
  *(float4*)(xio + base) = v;
  float s = v.x + v.y + v.z + v.w;
  float q = v.x * v.x + v.y * v.y + v.z * v.z + v.w * v.w;
#pragma unroll
  for (int off = 32; off > 0; off >>= 1) {
    s += __shfl_xor(s, off);
    q += __shfl_xor(q, off);
  }
  __shared__ float rs[4], rq[4];
  if ((tid & 63) == 0) { rs[tid >> 6] = s; rq[tid >> 6] = q; }
  __syncthreads();
  s = rs[0] + rs[1] + rs[2] + rs[3];
  q = rq[0] + rq[1] + rq[2] + rq[3];
  float mean = s * (1.f / 1024.f);
  float var = q * (1.f / 1024.f) - mean * mean;
  float rstd = rsqrtf(var + 1e-5f);
  float4 g = *(const float4*)(sc + c);
  float4 bb = *(const float4*)(bi + c);
  bf16x4 o4;
  o4.x = f2bf((v.x - mean) * rstd * g.x + bb.x);
  o4.y = f2bf((v.y - mean) * rstd * g.y + bb.y);
  o4.z = f2bf((v.z - mean) * rstd * g.z + bb.z);
  o4.w = f2bf((v.w - mean) * rstd * g.w + bb.w);
  *(bf16x4*)(out + (size_t)row * 1024 + c) = o4;
}

// ------ lnred4: x += 4 partials + gbias; LN(x) -> h  (bf16 partials) ------
__global__ __launch_bounds__(256) void lnred4_kernel(float* __restrict__ xio,
                                                     const short* __restrict__ P01,
                                                     const short* __restrict__ P23,
                                                     const float* __restrict__ gb,
                                                     const float* __restrict__ sc,
                                                     const float* __restrict__ bi,
                                                     short* __restrict__ out) {
  const size_t MN = (size_t)M_ROWS * 1024;
  int row = blockIdx.x, tid = threadIdx.x;
  int c = tid << 2;
  size_t base = (size_t)row * 1024 + c;
  float4 v = *(const float4*)(xio + base);
  bf16x4 p0 = *(const bf16x4*)(P01 + base);
  bf16x4 p1 = *(const bf16x4*)(P01 + MN + base);
  bf16x4 p2 = *(const bf16x4*)(P23 + base);
  bf16x4 p3 = *(const bf16x4*)(P23 + MN + base);
  float4 gv = *(const float4*)(gb + c);
  v.x += bf2f(p0.x) + bf2f(p1.x) + bf2f(p2.x) + bf2f(p3.x) + gv.x;
  v.y += bf2f(p0.y) + bf2f(p1.y) + bf2f(p2.y) + bf2f(p3.y) + gv.y;
  v.z += bf2f(p0.z) + bf2f(p1.z) + bf2f(p2.z) + bf2f(p3.z) + gv.z;
  v.w += bf2f(p0.w) + bf2f(p1.w) + bf2f(p2.w) + bf2f(p3.w) + gv.w;
  *(float4*)(xio + base) = v;
  float s = v.x + v.y + v.z + v.w;
  float q = v.x * v.x + v.y * v.y + v.z * v.z + v.w * v.w;
#pragma unroll
  for (int off = 32; off > 0; off >>= 1) {
    s += __shfl_xor(s, off);
    q += __shfl_xor(q, off);
  }
  __shared__ float rs[4], rq[4];
  if ((tid & 63) == 0) { rs[tid >> 6] = s; rq[tid >> 6] = q; }
  __syncthreads();
  s = rs[0] + rs[1] + rs[2] + rs[3];
  q = rq[0] + rq[1] + rq[2] + rq[3];
  float mean = s * (1.f / 1024.f);
  float var = q * (1.f / 1024.f) - mean * mean;
  float rstd = rsqrtf(var + 1e-5f);
  float4 g = *(const float4*)(sc + c);
  float4 bb = *(const float4*)(bi + c);
  bf16x4 o4;
  o4.x = f2bf((v.x - mean) * rstd * g.x + bb.x);
  o4.y = f2bf((v.y - mean) * rstd * g.y + bb.y);
  o4.z = f2bf((v.z - mean) * rstd * g.z + bb.z);
  o4.w = f2bf((v.w - mean) * rstd * g.w + bb.w);
  *(bf16x4*)(out + (size_t)row * 1024 + c) = o4;
}

// ------ GEMM3SK: 64x128 tile, BK=64, split-K=2, 3-buf never-drain; bf16 partials ------
__global__ __launch_bounds__(256) void gemm3sk_kernel(const short* __restrict__ A,
                                                      const short* __restrict__ Bt,
                                                      short* __restrict__ Pout,
                                                      int K, int N) {
  constexpr int ABY = 64 * 128;
  constexpr int BBY = 128 * 128;
  extern __shared__ char smem[];
  char* Asm = smem;
  char* Bsm = smem + 3 * ABY;
  const int NB = N >> 7;
  int nwg = 64 * NB;
  int bid = blockIdx.x;
  int wgid = (bid & 7) * (nwg >> 3) + (bid >> 3);
  int half = wgid >= (nwg >> 1);
  int w2 = wgid - half * (nwg >> 1);
  int bn = w2 >> 5, bm = w2 & 31;
  int kbase = half * (K >> 1);
  Pout += (size_t)half * M_ROWS * N;
  int tid = threadIdx.x;
  int lane = tid & 63, w = tid >> 6;
  int lr = lane & 15, lg = lane >> 4;
  int wn = w & 1, wm = w >> 1;

  const floatx4 FZ = {0.f, 0.f, 0.f, 0.f};
  floatx4 acc[2][4];
#pragma unroll
  for (int m = 0; m < 2; ++m)
#pragma unroll
    for (int n = 0; n < 4; ++n) acc[m][n] = FZ;

  size_t aoff[2], boff[4];
  {
    int rr = tid >> 3;
    int g = (tid & 7) ^ (rr & 7);
#pragma unroll
    for (int i = 0; i < 2; ++i)
      aoff[i] = (size_t)(bm * 64 + i * 32 + rr) * K + kbase + g * 8;
#pragma unroll
    for (int i = 0; i < 4; ++i)
      boff[i] = (size_t)(bn * 128 + i * 32 + rr) * K + kbase + g * 8;
  }

#define STA3(b, k0)                                                        \
  _Pragma("unroll") for (int i = 0; i < 2; ++i)                            \
    lds_cp16(A + aoff[i] + (k0), Asm + (b) * ABY + i * 4096 + tid * 16);
#define STB3(b, k0)                                                        \
  _Pragma("unroll") for (int i = 0; i < 4; ++i)                            \
    lds_cp16(Bt + boff[i] + (k0), Bsm + (b) * BBY + i * 4096 + tid * 16);
#define LDA3(b, kh)                                                        \
  _Pragma("unroll") for (int f = 0; f < 2; ++f) {                          \
    int lrow = wm * 32 + f * 16 + lr;                                      \
    af[f] = *(const bf16x8*)(Asm + (b) * ABY + lrow * 128 +                \
                             (((((kh) << 2) + lg) ^ (lrow & 7)) << 4));    \
  }
#define LDB3(b, kh)                                                        \
  _Pragma("unroll") for (int n = 0; n < 4; ++n) {                          \
    int lcol = wn * 64 + n * 16 + lr;                                      \
    bfr[n] = *(const bf16x8*)(Bsm + (b) * BBY + lcol * 128 +               \
                              (((((kh) << 2) + lg) ^ (lcol & 7)) << 4));   \
  }
#define MFMA3                                                              \
  __builtin_amdgcn_s_setprio(1);                                           \
  _Pragma("unroll") for (int f = 0; f < 2; ++f)                            \
  _Pragma("unroll") for (int n = 0; n < 4; ++n)                            \
    acc[f][n] = __builtin_amdgcn_mfma_f32_16x16x32_bf16(af[f], bfr[n],     \
                                                        acc[f][n], 0, 0, 0);\
  __builtin_amdgcn_s_setprio(0);

  const int nt = (K >> 1) >> 6;
  STA3(0, 0); STB3(0, 0);
  STA3(1, 64); STB3(1, 64);
  WVM(6);
  BARR;

  int cbuf = 0, sbuf = 2;
  for (int t = 0; t < nt; ++t) {
    bf16x8 af[2], bfr[4];
    bool pre = (t + 2 < nt);
    int k2 = (t + 2) << 6;
    if (pre) { STA3(sbuf, k2); }
    LDA3(cbuf, 0); LDB3(cbuf, 0);
    MFMA3;
    if (pre) { STB3(sbuf, k2); }
    LDA3(cbuf, 1); LDB3(cbuf, 1);
    MFMA3;
    if (pre) { WVM(6); } else { WVM(0); }
    BARR;
    cbuf = (cbuf == 2) ? 0 : cbuf + 1;
    sbuf = (sbuf == 2) ? 0 : sbuf + 1;
  }

#pragma unroll
  for (int n = 0; n < 4; ++n) {
    int col = (bn << 7) + wn * 64 + (n << 4) + lr;
#pragma unroll
    for (int m = 0; m < 2; ++m) {
      int row0 = bm * 64 + wm * 32 + (m << 4) + (lg << 2);
#pragma unroll
      for (int r = 0; r < 4; ++r)
        Pout[(size_t)(row0 + r) * N + col] = f2bf(acc[m][n][r]);
    }
  }
#undef STA3
#undef STB3
#undef LDA3
#undef LDB3
#undef MFMA3
}

// ------ GEMMW: 128x256 tile, 8 waves (wave 64x64), 3-buf never-drain. 144KB LDS ------
// VSPLIT: cols >=2048 (QKV's V section) written transposed to vtb, skipped in Cout.
template <bool BIAS, bool RELU, bool OUTBF16, bool VSPLIT>
__global__ __launch_bounds__(512) void gemmw_kernel(const short* __restrict__ A,
                                                    const short* __restrict__ Bt,
                                                    const float* __restrict__ bias,
                                                    void* __restrict__ Cout,
                                                    short* __restrict__ vtb,
                                                    int K, int N) {
  constexpr int ABY = 128 * 128;   // 16KB per A buf
  constexpr int BBY = 256 * 128;   // 32KB per B buf
  extern __shared__ char smem[];
  char* Asm = smem;                // 3 bufs
  char* Bsm = smem + 3 * ABY;
  const int NB = N >> 8;
  int nwg = 16 * NB;
  int bid = blockIdx.x;
  int wgid = (bid & 7) * (nwg >> 3) + (bid >> 3);
  int bn = wgid >> 4, bm = wgid & 15;               // bn-major
  int tid = threadIdx.x;
  int lane = tid & 63, w = tid >> 6;
  int lr = lane & 15, lg = lane >> 4;
  int wm = w >> 2, wn = w & 3;

  const floatx4 FZ = {0.f, 0.f, 0.f, 0.f};
  floatx4 acc[4][4];
#pragma unroll
  for (int m = 0; m < 4; ++m)
#pragma unroll
    for (int n = 0; n < 4; ++n) acc[m][n] = FZ;

  size_t aoff[2], boff[4];
  {
    int rr = tid >> 3;                               // 0..63
    int g = (tid & 7) ^ (rr & 7);
#pragma unroll
    for (int i = 0; i < 2; ++i)
      aoff[i] = (size_t)(bm * 128 + i * 64 + rr) * K + g * 8;
#pragma unroll
    for (int i = 0; i < 4; ++i)
      boff[i] = (size_t)(bn * 256 + i * 64 + rr) * K + g * 8;
  }

#define STAW(b, k0)                                                        \
  _Pragma("unroll") for (int i = 0; i < 2; ++i)                            \
    lds_cp16(A + aoff[i] + (k0), Asm + (b) * ABY + i * 8192 + tid * 16);
#define STBW(b, k0)                                                        \
  _Pragma("unroll") for (int i = 0; i < 4; ++i)                            \
    lds_cp16(Bt + boff[i] + (k0), Bsm + (b) * BBY + i * 8192 + tid * 16);
#define LDAW(b, kh)                                                        \
  _Pragma("unroll") for (int f = 0; f < 4; ++f) {                          \
    int lrow = wm * 64 + f * 16 + lr;                                      \
    af[f] = *(const bf16x8*)(Asm + (b) * ABY + lrow * 128 +                \
                             (((((kh) << 2) + lg) ^ (lrow & 7)) << 4));    \
  }
#define LDBW(b, kh)                                                        \
  _Pragma("unroll") for (int n = 0; n < 4; ++n) {                          \
    int lcol = wn * 64 + n * 16 + lr;                                      \
    bfr[n] = *(const bf16x8*)(Bsm + (b) * BBY + lcol * 128 +               \
                              (((((kh) << 2) + lg) ^ (lcol & 7)) << 4));   \
  }
#define MFMAW                                                              \
  __builtin_amdgcn_s_setprio(1);                                           \
  _Pragma("unroll") for (int f = 0; f < 4; ++f)                            \
  _Pragma("unroll") for (int n = 0; n < 4; ++n)                            \
    acc[f][n] = __builtin_amdgcn_mfma_f32_16x16x32_bf16(af[f], bfr[n],     \
                                                        acc[f][n], 0, 0, 0);\
  __builtin_amdgcn_s_setprio(0);

  const int nt = K >> 6;
  STAW(0, 0); STBW(0, 0);
  STAW(1, 64); STBW(1, 64);
  WVM(6);
  BARR;

  int cbuf = 0, sbuf = 2;
  for (int t = 0; t < nt; ++t) {
    bf16x8 af[4], bfr[4];
    bool pre = (t + 2 < nt);
    int k2 = (t + 2) << 6;
    if (pre) { STAW(sbuf, k2); }
    LDAW(cbuf, 0); LDBW(cbuf, 0);
    MFMAW;
    if (pre) { STBW(sbuf, k2); }
    LDAW(cbuf, 1); LDBW(cbuf, 1);
    MFMAW;
    if (pre) { WVM(6); } else { WVM(0); }
    BARR;
    cbuf = (cbuf == 2) ? 0 : cbuf + 1;
    sbuf = (sbuf == 2) ? 0 : sbuf + 1;
  }

#pragma unroll
  for (int n = 0; n < 4; ++n) {
    int col = (bn << 8) + wn * 64 + (n << 4) + lr;
    float bv = 0.f;
    if (BIAS) bv = bias[col];
#pragma unroll
    for (int m = 0; m < 4; ++m) {
      int row0 = bm * 128 + wm * 64 + (m << 4) + (lg << 2);
      if (VSPLIT && col >= 2048) {
        // V section: write transposed to vtb[b*16+head][hs][t], 4 consecutive t
        int hc = col - 2048;
        int brow = row0 >> 10, t0 = row0 & 1023;
        ushort4 pk;
        pk.x = (unsigned short)f2bf(acc[m][n][0]);
        pk.y = (unsigned short)f2bf(acc[m][n][1]);
        pk.z = (unsigned short)f2bf(acc[m][n][2]);
        pk.w = (unsigned short)f2bf(acc[m][n][3]);
        *(ushort4*)(vtb + ((size_t)(((brow << 4) + (hc >> 6)) << 6) + (hc & 63)) * 1024 + t0) = pk;
      } else {
#pragma unroll
        for (int r = 0; r < 4; ++r) {
          size_t idx = (size_t)(row0 + r) * N + col;
          float val = acc[m][n][r] + bv;
          if (RELU) val = fmaxf(val, 0.f);
          if (OUTBF16) ((short*)Cout)[idx] = f2bf(val);
          else ((float*)Cout)[idx] = val;
        }
      }
    }
  }
#undef STAW
#undef STBW
#undef LDAW
#undef LDBW
#undef MFMAW
}

// ------ GEMMWSK: gemmw with split-K=4, bf16 partials (parts 0,1->P01; 2,3->P23) ------
__global__ __launch_bounds__(512) void gemmwsk_kernel(const short* __restrict__ A,
                                                      const short* __restrict__ Bt,
                                                      short* __restrict__ P01,
                                                      short* __restrict__ P23,
                                                      int K, int N) {
  constexpr int ABY = 128 * 128;
  constexpr int BBY = 256 * 128;
  extern __shared__ char smem[];
  char* Asm = smem;
  char* Bsm = smem + 3 * ABY;
  const int NB = N >> 8;
  int nwg = 16 * NB * 4;
  int bid = blockIdx.x;
  int wgid = (bid & 7) * (nwg >> 3) + (bid >> 3);
  int per = nwg >> 2;
  int part = wgid / per;
  int w2 = wgid - part * per;
  int bn = w2 >> 4, bm = w2 & 15;
  int kbase = part * (K >> 2);
  short* Pout = (part < 2 ? P01 + (size_t)part * M_ROWS * N
                          : P23 + (size_t)(part - 2) * M_ROWS * N);
  int tid = threadIdx.x;
  int lane = tid & 63, w = tid >> 6;
  int lr = lane & 15, lg = lane >> 4;
  int wm = w >> 2, wn = w & 3;

  const floatx4 FZ = {0.f, 0.f, 0.f, 0.f};
  floatx4 acc[4][4];
#pragma unroll
  for (int m = 0; m < 4; ++m)
#pragma unroll
    for (int n = 0; n < 4; ++n) acc[m][n] = FZ;

  size_t aoff[2], boff[4];
  {
    int rr = tid >> 3;
    int g = (tid & 7) ^ (rr & 7);
#pragma unroll
    for (int i = 0; i < 2; ++i)
      aoff[i] = (size_t)(bm * 128 + i * 64 + rr) * K + kbase + g * 8;
#pragma unroll
    for (int i = 0; i < 4; ++i)
      boff[i] = (size_t)(bn * 256 + i * 64 + rr) * K + kbase + g * 8;
  }

#define STAW(b, k0)                                                        \
  _Pragma("unroll") for (int i = 0; i < 2; ++i)                            \
    lds_cp16(A + aoff[i] + (k0), Asm + (b) * ABY + i * 8192 + tid * 16);
#define STBW(b, k0)                                                        \
  _Pragma("unroll") for (int i = 0; i < 4; ++i)                            \
    lds_cp16(Bt + boff[i] + (k0), Bsm + (b) * BBY + i * 8192 + tid * 16);
#define LDAW(b, kh)                                                        \
  _Pragma("unroll") for (int f = 0; f < 4; ++f) {                          \
    int lrow = wm * 64 + f * 16 + lr;                                      \
    af[f] = *(const bf16x8*)(Asm + (b) * ABY + lrow * 128 +                \
                             (((((kh) << 2) + lg) ^ (lrow & 7)) << 4));    \
  }
#define LDBW(b, kh)                                                        \
  _Pragma("unroll") for (int n = 0; n < 4; ++n) {                          \
    int lcol = wn * 64 + n * 16 + lr;                                      \
    bfr[n] = *(const bf16x8*)(Bsm + (b) * BBY + lcol * 128 +               \
                              (((((kh) << 2) + lg) ^ (lcol & 7)) << 4));   \
  }
#define MFMAW                                                              \
  __builtin_amdgcn_s_setprio(1);                                           \
  _Pragma("unroll") for (int f = 0; f < 4; ++f)                            \
  _Pragma("unroll") for (int n = 0; n < 4; ++n)                            \
    acc[f][n] = __builtin_amdgcn_mfma_f32_16x16x32_bf16(af[f], bfr[n],     \
                                                        acc[f][n], 0, 0, 0);\
  __builtin_amdgcn_s_setprio(0);

  const int nt = (K >> 2) >> 6;
  STAW(0, 0); STBW(0, 0);
  STAW(1, 64); STBW(1, 64);
  WVM(6);
  BARR;

  int cbuf = 0, sbuf = 2;
  for (int t = 0; t < nt; ++t) {
    bf16x8 af[4], bfr[4];
    bool pre = (t + 2 < nt);
    int k2 = (t + 2) << 6;
    if (pre) { STAW(sbuf, k2); }
    LDAW(cbuf, 0); LDBW(cbuf, 0);
    MFMAW;
    if (pre) { STBW(sbuf, k2); }
    LDAW(cbuf, 1); LDBW(cbuf, 1);
    MFMAW;
    if (pre) { WVM(6); } else { WVM(0); }
    BARR;
    cbuf = (cbuf == 2) ? 0 : cbuf + 1;
    sbuf = (sbuf == 2) ? 0 : sbuf + 1;
  }

#pragma unroll
  for (int n = 0; n < 4; ++n) {
    int col = (bn << 8) + wn * 64 + (n << 4) + lr;
#pragma unroll
    for (int m = 0; m < 4; ++m) {
      int row0 = bm * 128 + wm * 64 + (m << 4) + (lg << 2);
#pragma unroll
      for (int r = 0; r < 4; ++r)
        Pout[(size_t)(row0 + r) * N + col] = f2bf(acc[m][n][r]);
    }
  }
#undef STAW
#undef STBW
#undef LDAW
#undef LDBW
#undef MFMAW
}

// ---------------- GEMM8: 256x256 8-phase, dynamic LDS 128KB (LM head) ----------------
template <bool BIAS, bool OUTBF16>
__global__ __launch_bounds__(512) void gemm8_kernel(const short* __restrict__ A,
                                                    const short* __restrict__ Bt,
                                                    const float* __restrict__ bias,
                                                    void* __restrict__ Cout,
                                                    int K, int N) {
  extern __shared__ char smem[];
  char* Asm = smem;            // [buf][chunk][128 rows][128B]
  char* Bsm = smem + 65536;    // [buf][256 cols][128B]
  const int NB = N >> 8;
  int nwg = 8 * NB;
  int bid = blockIdx.x;
  int wgid = (bid & 7) * (nwg >> 3) + (bid >> 3);
  int bm = wgid & 7, bn = wgid >> 3;
  int tid = threadIdx.x;
  int lane = tid & 63, w = tid >> 6;
  int lr = lane & 15, lg = lane >> 4;
  int wm = w >> 2, wn = w & 3;

  const floatx4 FZ = {0.f, 0.f, 0.f, 0.f};
  floatx4 acc[8][4];
#pragma unroll
  for (int m = 0; m < 8; ++m)
#pragma unroll
    for (int n = 0; n < 4; ++n) acc[m][n] = FZ;

  size_t aoff[2][2], boff[4];
  {
    int rr = tid >> 3;
    int g = (tid & 7) ^ (rr & 7);
#pragma unroll
    for (int c = 0; c < 2; ++c)
#pragma unroll
      for (int i = 0; i < 2; ++i) {
        int lrow = i * 64 + rr;
        int grow = (lrow & 63) + ((lrow >> 6) << 7) + (c << 6);
        aoff[c][i] = (size_t)(bm * 256 + grow) * K + g * 8;
      }
#pragma unroll
    for (int i = 0; i < 4; ++i)
      boff[i] = (size_t)(bn * 256 + i * 64 + rr) * K + g * 8;
  }

  bf16x8 areg[4], breg[2][4];

#define LDA8(chunk, kh)                                                          \
  _Pragma("unroll") for (int f = 0; f < 4; ++f) {                                \
    int lrow = wm * 64 + f * 16 + lr;                                            \
    areg[f] = *(const bf16x8*)(Asm + buf * 32768 + (chunk) * 16384 + lrow * 128  \
                               + (((((kh) << 2) + lg) ^ (lrow & 7)) << 4));      \
  }
#define LDB8(kh)                                                                 \
  _Pragma("unroll") for (int n = 0; n < 4; ++n) {                                \
    int lcol = wn * 64 + n * 16 + lr;                                            \
    breg[kh][n] = *(const bf16x8*)(Bsm + buf * 32768 + lcol * 128                \
                                   + (((((kh) << 2) + lg) ^ (lcol & 7)) << 4));  \
  }
#define MFMA16(mh, kh)                                                           \
  __builtin_amdgcn_s_setprio(1);                                                 \
  _Pragma("unroll") for (int f = 0; f < 4; ++f)                                  \
  _Pragma("unroll") for (int n = 0; n < 4; ++n)                                  \
    acc[(mh) * 4 + f][n] = __builtin_amdgcn_mfma_f32_16x16x32_bf16(              \
        areg[f], breg[kh][n], acc[(mh) * 4 + f][n], 0, 0, 0);                    \
  __builtin_amdgcn_s_setprio(0);
#define STA8(chunk, dstbuf, k0)                                                  \
  _Pragma("unroll") for (int i = 0; i < 2; ++i)                                  \
    lds_cp16(A + aoff[chunk][i] + (k0),                                          \
             Asm + (dstbuf) * 32768 + (chunk) * 16384 + i * 8192 + tid * 16);
#define STB8(dstbuf, k0)                                                         \
  _Pragma("unroll") for (int i = 0; i < 4; ++i)                                  \
    lds_cp16(Bt + boff[i] + (k0),                                                \
             Bsm + (dstbuf) * 32768 + i * 8192 + tid * 16);

  const int nt = K >> 6;
  STA8(0, 0, 0); STB8(0, 0); STA8(1, 0, 0);
  WVM(2);
  BARR;

  int buf = 0;
  for (int t = 0; t < nt - 1; ++t) {
    int k1 = (t + 1) << 6;
    int ob = buf ^ 1;
    LDA8(0, 0); LDB8(0);
    STA8(0, ob, k1);
    BARR;
    MFMA16(0, 0);
    BARR;
    LDA8(0, 1); LDB8(1);
    STB8(ob, k1);
    WVM(6);
    BARR;
    MFMA16(0, 1);
    BARR;
    LDA8(1, 0);
    STA8(1, ob, k1);
    BARR;
    MFMA16(1, 0);
    BARR;
    LDA8(1, 1);
    WVM(2);
    BARR;
    MFMA16(1, 1);
    BARR;
    buf ^= 1;
  }
  LDA8(0, 0); LDB8(0);
  MFMA16(0, 0);
  LDA8(0, 1); LDB8(1);
  MFMA16(0, 1);
  WVM(0);
  BARR;
  LDA8(1, 0);
  MFMA16(1, 0);
  LDA8(1, 1);
  MFMA16(1, 1);

#pragma unroll
  for (int n = 0; n < 4; ++n) {
    int col = (bn << 8) + (wn << 6) + (n << 4) + lr;
    float bv = 0.f;
    if (BIAS) bv = bias[col];
#pragma unroll
    for (int m = 0; m < 8; ++m) {
      int row0 = (bm << 8) + (wm << 7) + (m << 4) + (lg << 2);
#pragma unroll
      for (int r = 0; r < 4; ++r) {
        size_t idx = (size_t)(row0 + r) * N + col;
        float val = acc[m][n][r] + bv;
        if (OUTBF16) ((short*)Cout)[idx] = f2bf(val);
        else ((float*)Cout)[idx] = val;
      }
    }
  }
#undef LDA8
#undef LDB8
#undef MFMA16
#undef STA8
#undef STB8
}

// ---------------- flash attention: KVBLK=128, mask-free main loop + trimmed epilogue ----------------
__global__ __launch_bounds__(256) void attn_kernel(const short* __restrict__ qkv,
                                                   const short* __restrict__ vt,
                                                   short* __restrict__ out) {
  int bh = blockIdx.x;
  int qt = blockIdx.y;
  int b = bh >> 4, hh = bh & 15;
  int tid = threadIdx.x;
  int lane = tid & 63, w = tid >> 6;
  int lr = lane & 15, lg = lane >> 4;

  __shared__ short Ks[128 * 64];    // [kv][hs], 128B rows, granule ^= row&7
  __shared__ short Vs[64 * 128];    // V^T [hs][kv], 256B rows, granule ^= row&15
  __shared__ short Ps[4][16 * 132]; // per-wave P strip [16 q][132 kv-stride]

  const floatx4 FZ = {0.f, 0.f, 0.f, 0.f};
  const float C2 = 0.18033688f;     // HS^-0.5 * log2(e)
  const short* qb = qkv + (size_t)((b << 10) + (qt << 6) + (w << 4) + lr) * 3072 + (hh << 6);
  bf16x8 qf0 = *(const bf16x8*)(qb + (lg << 3));
  bf16x8 qf1 = *(const bf16x8*)(qb + 32 + (lg << 3));

  floatx4 o[4];
  float mrun[4], lrun[4];
#pragma unroll
  for (int r = 0; r < 4; ++r) { o[r] = FZ; mrun[r] = -3e38f; lrun[r] = 0.f; }

  int krow = tid >> 3, kgr = tid & 7;     // K staging: 32 rows/inst
  int vrow = tid >> 4, vgr = tid & 15;    // V staging: 16 rows/inst
  const short* kB = qkv + (size_t)(b << 10) * 3072 + 1024 + (hh << 6);
  const short* vB = vt + (size_t)(bh << 6) * 1024;

#define STKV(JT)                                                           \
  _Pragma("unroll") for (int i = 0; i < 4; ++i) {                          \
    int r = (i << 5) + krow;                                               \
    lds_cp16(kB + (size_t)(((JT) << 7) + r) * 3072 + ((kgr ^ (r & 7)) << 3), \
             (char*)Ks + i * 4096 + tid * 16);                             \
  }                                                                        \
  _Pragma("unroll") for (int i = 0; i < 4; ++i) {                          \
    int r = (i << 4) + vrow;                                               \
    lds_cp16(vB + (size_t)r * 1024 + ((JT) << 7) + ((vgr ^ (r & 15)) << 3), \
             (char*)Vs + i * 4096 + tid * 16);                             \
  }

#define CHUNK_COMPUTE(NF, MASK, JT)                                        \
  {                                                                        \
    const char* KsB = (const char*)Ks;                                     \
    const char* VsB = (const char*)Vs;                                     \
    floatx4 s[NF];                                                         \
    _Pragma("unroll") for (int f = 0; f < NF; ++f) {                       \
      int rk = (f << 4) + lr;                                              \
      int sw = rk & 7;                                                     \
      bf16x8 kf0 = *(const bf16x8*)(KsB + rk * 128 + ((lg ^ sw) << 4));    \
      bf16x8 kf1 = *(const bf16x8*)(KsB + rk * 128 + (((4 + lg) ^ sw) << 4)); \
      floatx4 t0 = __builtin_amdgcn_mfma_f32_16x16x32_bf16(qf0, kf0, FZ, 0, 0, 0); \
      s[f] = __builtin_amdgcn_mfma_f32_16x16x32_bf16(qf1, kf1, t0, 0, 0, 0); \
    }                                                                      \
    int qrow0 = (qt << 6) + (w << 4) + (lg << 2);                          \
    _Pragma("unroll") for (int f = 0; f < NF; ++f)                         \
    _Pragma("unroll") for (int r = 0; r < 4; ++r) {                        \
      float sv = s[f][r] * C2;                                             \
      if (MASK && (((JT) << 7) + (f << 4) + lr > qrow0 + r)) sv = -3e38f;  \
      s[f][r] = sv;                                                        \
    }                                                                      \
    float mt[4] = {-3e38f, -3e38f, -3e38f, -3e38f};                        \
    _Pragma("unroll") for (int f = 0; f < NF; ++f)                         \
    _Pragma("unroll") for (int r = 0; r < 4; ++r) mt[r] = fmaxf(mt[r], s[f][r]); \
    _Pragma("unroll") for (int off = 1; off < 16; off <<= 1)               \
    _Pragma("unroll") for (int r = 0; r < 4; ++r)                          \
      mt[r] = fmaxf(mt[r], __shfl_xor(mt[r], off));                        \
    float corr[4], psum[4];                                                \
    _Pragma("unroll") for (int r = 0; r < 4; ++r) {                        \
      float mnew = fmaxf(mrun[r], mt[r]);                                  \
      corr[r] = exp2f(mrun[r] - mnew);                                     \
      mrun[r] = mnew;                                                      \
      float ps = 0.f;                                                      \
      _Pragma("unroll") for (int f = 0; f < NF; ++f) {                     \
        float e = exp2f(s[f][r] - mnew);                                   \
        s[f][r] = e;                                                       \
        ps += e;                                                           \
      }                                                                    \
      psum[r] = ps;                                                        \
    }                                                                      \
    _Pragma("unroll") for (int off = 1; off < 16; off <<= 1)               \
    _Pragma("unroll") for (int r = 0; r < 4; ++r)                          \
      psum[r] += __shfl_xor(psum[r], off);                                 \
    floatx4 cv;                                                            \
    _Pragma("unroll") for (int r = 0; r < 4; ++r) {                        \
      lrun[r] = lrun[r] * corr[r] + psum[r];                               \
      cv[r] = corr[r];                                                     \
    }                                                                      \
    _Pragma("unroll") for (int f = 0; f < 4; ++f) o[f] *= cv;              \
    char* PsB = (char*)&Ps[w][0];                                          \
    _Pragma("unroll") for (int f = 0; f < NF; ++f)                         \
    _Pragma("unroll") for (int r = 0; r < 4; ++r)                          \
      *(short*)(PsB + ((lg << 2) + r) * 264 + (((f << 4) + lr) << 1)) =    \
          f2bf(s[f][r]);                                                   \
    _Pragma("unroll") for (int kk = 0; kk < (NF >> 1); ++kk) {             \
      const char* pb = PsB + lr * 264 + (kk << 6) + (lg << 4);             \
      union { struct { bf16x4 lo, hi; } h2; bf16x8 v; } pu;                \
      pu.h2.lo = *(const bf16x4*)pb;                                       \
      pu.h2.hi = *(const bf16x4*)(pb + 8);                                 \
      bf16x8 pa = pu.v;                                                    \
      _Pragma("unroll") for (int f = 0; f < 4; ++f) {                      \
        int rv = (f << 4) + lr;                                            \
        bf16x8 vf = *(const bf16x8*)(VsB + rv * 256 +                      \
                                     ((((kk << 2) + lg) ^ (rv & 15)) << 4)); \
        o[f] = __builtin_amdgcn_mfma_f32_16x16x32_bf16(pa, vf, o[f], 0, 0, 0); \
      }                                                                    \
    }                                                                      \
  }

  const int nfull = qt >> 1;              // chunks with no masking at all
  for (int jt = 0; jt < nfull; ++jt) {
    STKV(jt);
    WVM(0);
    BARR;
    CHUNK_COMPUTE(8, false, jt)
    BARR;                                 // close reads before next staging
  }
  // epilogue chunk (block-uniform branch on qt parity)
  STKV(nfull);
  WVM(0);
  BARR;
  if (qt & 1) {
    CHUNK_COMPUTE(8, true, nfull)
  } else {
    CHUNK_COMPUTE(4, true, nfull)         // upper 64 kv fully masked -> skip
  }
#undef STKV
#undef CHUNK_COMPUTE

#pragma unroll
  for (int f = 0; f < 4; ++f) {
#pragma unroll
    for (int r = 0; r < 4; ++r) {
      int row = (qt << 6) + (w << 4) + (lg << 2) + r;
      int col = (hh << 6) + (f << 4) + lr;
      out[(size_t)((b << 10) + row) * 1024 + col] = f2bf(o[f][r] / lrun[r]);
    }
  }
}

// ---------------- launch ----------------
extern "C" void kernel_launch(void* const* d_in, const int* in_sizes, int n_in,
                              void* d_out, int out_size, void* d_ws, size_t ws_size,
                              hipStream_t stream) {
  const int*   tokens  = (const int*)d_in[0];
  const float* tok_emb = (const float*)d_in[1];
  const float* pos_emb = (const float*)d_in[2];
  const float* Wq  = (const float*)d_in[3];
  const float* Wk  = (const float*)d_in[4];
  const float* Wv  = (const float*)d_in[5];
  const float* Wo  = (const float*)d_in[6];
  const float* bo  = (const float*)d_in[7];
  const float* ln1s = (const float*)d_in[8];
  const float* ln1b = (const float*)d_in[9];
  const float* ln2s = (const float*)d_in[10];
  const float* ln2b = (const float*)d_in[11];
  const float* W1  = (const float*)d_in[12];
  const float* b1  = (const float*)d_in[13];
  const float* W2  = (const float*)d_in[14];
  const float* b2  = (const float*)d_in[15];
  const float* lnfs = (const float*)d_in[16];
  const float* lnfb = (const float*)d_in[17];
  const float* Wlm = (const float*)d_in[18];
  const float* blm = (const float*)d_in[19];

  short* wqkvT = (short*)d_ws;                               // [L][3072][1024]
  short* woT   = wqkvT + (size_t)L_LAYERS * 3072 * 1024;     // [L][1024][1024]
  short* w1T   = woT   + (size_t)L_LAYERS * 1024 * 1024;     // [L][4096][1024]
  short* w2T   = w1T   + (size_t)L_LAYERS * 4096 * 1024;     // [L][1024][4096]
  short* wlmT  = w2T   + (size_t)L_LAYERS * 1024 * 4096;     // [32000][1024]
  float* x     = (float*)(wlmT + (size_t)V_VOCAB * 1024);    // [2048][1024] f32
  short* h     = (short*)(x + (size_t)M_ROWS * 1024);        // [2048][1024] bf16
  short* qkv   = h + (size_t)M_ROWS * 1024;                  // [2048][3072] bf16
  short* vtb   = qkv + (size_t)M_ROWS * 3072;                // [32][64][1024] bf16
  short* attnb = vtb + (size_t)B_BATCH * N_HEAD * H_SZ * T_SEQ; // [2048][1024]
  short* mid   = attnb + (size_t)M_ROWS * 1024;              // [2048][4096] bf16
  short* psum  = mid + (size_t)M_ROWS * 4096;                // 2x[2048][1024] bf16
  short* psum1 = psum + (size_t)M_ROWS * 1024;
  // split-K parts 2,3 reuse the dead qkv+vtb region (8MB fits easily)
  short* psum23 = qkv;

  dim3 blk(256, 1, 1);

  // raise dynamic-LDS caps (idempotent, host-side, capture-safe)
  (void)hipFuncSetAttribute(reinterpret_cast<const void*>(&gemm8_kernel<true, false>),
                            hipFuncAttributeMaxDynamicSharedMemorySize, 131072);
  (void)hipFuncSetAttribute(reinterpret_cast<const void*>(&gemm3sk_kernel),
                            hipFuncAttributeMaxDynamicSharedMemorySize, 73728);
  (void)hipFuncSetAttribute(reinterpret_cast<const void*>(&gemmw_kernel<false, false, true, true>),
                            hipFuncAttributeMaxDynamicSharedMemorySize, 147456);
  (void)hipFuncSetAttribute(reinterpret_cast<const void*>(&gemmw_kernel<true, true, true, false>),
                            hipFuncAttributeMaxDynamicSharedMemorySize, 147456);
  (void)hipFuncSetAttribute(reinterpret_cast<const void*>(&gemmwsk_kernel),
                            hipFuncAttributeMaxDynamicSharedMemorySize, 147456);

  // ---- weight prep ----
  transpose_cvt<<<dim3(16, 16, 6), blk, 0, stream>>>(Wq, wqkvT,             1024, 1024, 1048576, 3072 * 1024);
  transpose_cvt<<<dim3(16, 16, 6), blk, 0, stream>>>(Wk, wqkvT + 1048576,   1024, 1024, 1048576, 3072 * 1024);
  transpose_cvt<<<dim3(16, 16, 6), blk, 0, stream>>>(Wv, wqkvT + 2097152,   1024, 1024, 1048576, 3072 * 1024);
  transpose_cvt<<<dim3(16, 16, 6), blk, 0, stream>>>(Wo, woT,               1024, 1024, 1048576, 1048576);
  transpose_cvt<<<dim3(16, 64, 6), blk, 0, stream>>>(W1, w1T,               1024, 4096, 4194304, 4194304);
  transpose_cvt<<<dim3(64, 16, 6), blk, 0, stream>>>(W2, w2T,               4096, 1024, 4194304, 4194304);
  transpose_cvt<<<dim3(16, 500, 1), blk, 0, stream>>>(Wlm, wlmT,            1024, V_VOCAB, 0, 0);

  // ---- forward ----
  embedln_kernel<<<M_ROWS, blk, 0, stream>>>(tokens, tok_emb, pos_emb, x, ln1s, ln1b, h);

  for (int l = 0; l < L_LAYERS; ++l) {
    if (l > 0) {
      // fused: x += 4 mlp2 partials + b2[l-1]; h = LN1_l(x)
      lnred4_kernel<<<M_ROWS, blk, 0, stream>>>(x, psum, psum23, b2 + (l - 1) * 1024,
                                                ln1s + l * 1024, ln1b + l * 1024, h);
    }
    // QKV: 128x256-tile 8-wave; V section written transposed to vtb (VSPLIT)
    gemmw_kernel<false, false, true, true><<<16 * 12, dim3(512, 1, 1), 147456, stream>>>(
        h, wqkvT + (size_t)l * 3072 * 1024, nullptr, qkv, vtb, 1024, 3072);
    attn_kernel<<<dim3(32, 16), blk, 0, stream>>>(qkv, vtb, attnb);
    // proj split-K=2 -> bf16 partials (512 blocks, nt=8)
    gemm3sk_kernel<<<64 * 8, blk, 73728, stream>>>(
        attnb, woT + (size_t)l * 1048576, psum, 1024, 1024);
    // fused: x += proj partials + bo[l]; h = LN2_l(x)
    lnred_kernel<<<M_ROWS, blk, 0, stream>>>(x, psum, psum1, bo + l * 1024,
                                             ln2s + l * 1024, ln2b + l * 1024, h);
    // MLP1: 128x256-tile 8-wave (grid 256)
    gemmw_kernel<true, true, true, false><<<16 * 16, dim3(512, 1, 1), 147456, stream>>>(
        h, w1T + (size_t)l * 4194304, b1 + l * 4096, mid, nullptr, 1024, 4096);
    // MLP2 split-K=4 -> bf16 partials (parts 2,3 over dead qkv buffer; nt=16)
    gemmwsk_kernel<<<16 * 16, dim3(512, 1, 1), 147456, stream>>>(
        mid, w2T + (size_t)l * 4194304, psum, psum23, 4096, 1024);
  }

  // fused final: x += 4 mlp2 partials + b2[5]; h = LNf(x)
  lnred4_kernel<<<M_ROWS, blk, 0, stream>>>(x, psum, psum23, b2 + 5 * 1024,
                                            lnfs, lnfb, h);
  gemm8_kernel<true, false><<<dim3(8 * 125), dim3(512, 1, 1), 131072, stream>>>(
      h, wlmT, blm, (float*)d_out, 1024, V_VOCAB);
}

// Round 14
// 999.794 us; speedup vs baseline: 1.0498x; 1.0064x over previous
//
#include <hip/hip_runtime.h>
#include <hip/hip_bf16.h>
#include <stdint.h>

// ---- fixed model dims ----
#define L_LAYERS 6
#define D_MODEL  1024
#define N_HEAD   16
#define H_SZ     64
#define T_SEQ    1024
#define B_BATCH  2
#define M_ROWS   2048   // B*T
#define V_VOCAB  32000

typedef __attribute__((ext_vector_type(8))) short bf16x8;
typedef __attribute__((ext_vector_type(4))) short bf16x4;
typedef __attribute__((ext_vector_type(4))) float floatx4;

static __device__ __forceinline__ short f2bf(float f) {
  __hip_bfloat16 h = __float2bfloat16(f);
  return *reinterpret_cast<short*>(&h);
}
static __device__ __forceinline__ float bf2f(short s) {
  unsigned u = ((unsigned)(unsigned short)s) << 16;
  return *reinterpret_cast<float*>(&u);
}

static __device__ __forceinline__ void lds_cp16(const void* g, void* l) {
  // async global->LDS, 16B/lane; LDS dest = wave-uniform base + lane*16
  __builtin_amdgcn_global_load_lds(
      (const __attribute__((address_space(1))) uint32_t*)g,
      (__attribute__((address_space(3))) uint32_t*)l, 16, 0, 0);
}

#define WVM(n) asm volatile("s_waitcnt vmcnt(" #n ")" ::: "memory")
#define BARR __builtin_amdgcn_s_barrier()

// ---------------- weight prep: f32 [R][C] -> bf16 [C][R], batched over z ----------------
__global__ __launch_bounds__(256) void transpose_cvt(const float* __restrict__ in,
                                                     short* __restrict__ out,
                                                     int R, int C,
                                                     long in_stride, long out_stride) {
  in  += (size_t)blockIdx.z * in_stride;
  out += (size_t)blockIdx.z * out_stride;
  __shared__ float tile[64][65];
  int rt = blockIdx.x, ct = blockIdx.y;
  int tid = threadIdx.x;
  int r0 = tid >> 4;
  int c0 = (tid & 15) << 2;
  const float* ip = in + (size_t)(rt * 64) * C + ct * 64;
#pragma unroll
  for (int p = 0; p < 4; ++p) {
    int r = r0 + (p << 4);
    float4 v = *(const float4*)(ip + (size_t)r * C + c0);
    tile[r][c0] = v.x; tile[r][c0 + 1] = v.y; tile[r][c0 + 2] = v.z; tile[r][c0 + 3] = v.w;
  }
  __syncthreads();
  short* op = out + (size_t)(ct * 64) * R + rt * 64;
#pragma unroll
  for (int p = 0; p < 2; ++p) {
    int c = (tid >> 3) + (p << 5);
    int r8 = (tid & 7) << 3;
    bf16x8 o8;
#pragma unroll
    for (int j = 0; j < 8; ++j) o8[j] = f2bf(tile[r8 + j][c]);
    *(bf16x8*)(op + (size_t)c * R + r8) = o8;
  }
}

// ---------------- fused embedding + LN1(layer0): writes x (f32) and h (bf16) ----------------
__global__ __launch_bounds__(256) void embedln_kernel(const int* __restrict__ tokens,
                                                      const float* __restrict__ tok_emb,
                                                      const float* __restrict__ pos_emb,
                                                      float* __restrict__ x,
                                                      const float* __restrict__ sc,
                                                      const float* __restrict__ bi,
                                                      short* __restrict__ out) {
  int row = blockIdx.x, tid = threadIdx.x;
  int t = row & 1023;
  int tok = tokens[row];
  int c = tid << 2;
  float4 e = *(const float4*)(tok_emb + (size_t)tok * 1024 + c);
  float4 p = *(const float4*)(pos_emb + (size_t)t * 1024 + c);
  float4 v; v.x = e.x + p.x; v.y = e.y + p.y; v.z = e.z + p.z; v.w = e.w + p.w;
  *(float4*)(x + (size_t)row * 1024 + c) = v;
  float s = v.x + v.y + v.z + v.w;
  float q = v.x * v.x + v.y * v.y + v.z * v.z + v.w * v.w;
#pragma unroll
  for (int off = 32; off > 0; off >>= 1) {
    s += __shfl_xor(s, off);
    q += __shfl_xor(q, off);
  }
  __shared__ float rs[4], rq[4];
  if ((tid & 63) == 0) { rs[tid >> 6] = s; rq[tid >> 6] = q; }
  __syncthreads();
  s = rs[0] + rs[1] + rs[2] + rs[3];
  q = rq[0] + rq[1] + rq[2] + rq[3];
  float mean = s * (1.f / 1024.f);
  float var = q * (1.f / 1024.f) - mean * mean;
  float rstd = rsqrtf(var + 1e-5f);
  float4 g = *(const float4*)(sc + c);
  float4 bb = *(const float4*)(bi + c);
  bf16x4 o4;
  o4.x = f2bf((v.x - mean) * rstd * g.x + bb.x);
  o4.y = f2bf((v.y - mean) * rstd * g.y + bb.y);
  o4.z = f2bf((v.z - mean) * rstd * g.z + bb.z);
  o4.w = f2bf((v.w - mean) * rstd * g.w + bb.w);
  *(bf16x4*)(out + (size_t)row * 1024 + c) = o4;
}

// ------ lnred: x += P0 + P1 + gbias; then LN(x) -> h  (bf16 partials) ------
__global__ __launch_bounds__(256) void lnred_kernel(float* __restrict__ xio,
                                                    const short* __restrict__ P0,
                                                    const short* __restrict__ P1,
                                                    const float* __restrict__ gb,
                                                    const float* __restrict__ sc,
                                                    const float* __restrict__ bi,
                                                    short* __restrict__ out) {
  int row = blockIdx.x, tid = threadIdx.x;
  int c = tid << 2;
  size_t base = (size_t)row * 1024 + c;
  float4 v = *(const float4*)(xio + base);
  bf16x4 p0 = *(const bf16x4*)(P0 + base);
  bf16x4 p1 = *(const bf16x4*)(P1 + base);
  float4 gv = *(const float4*)(gb + c);
  v.x += bf2f(p0.x) + bf2f(p1.x) + gv.x;
  v.y += bf2f(p0.y) + bf2f(p1.y) + gv.y;
  v.z += bf2f(p0.z) + bf2f(p1.z) + gv.z;
  v.w += bf2f(p0.w) + bf2f(p1.w) + gv.w;
  *(float4*)(xio + base) = v;
  float s = v.x + v.y + v.z + v.w;
  float q = v.x * v.x + v.y * v.y + v.z * v.z + v.w * v.w;
#pragma unroll
  for (int off = 32; off > 0; off >>= 1) {
    s += __shfl_xor(s, off);
    q += __shfl_xor(q, off);
  }
  __shared__ float rs[4], rq[4];
  if ((tid & 63) == 0) { rs[tid >> 6] = s; rq[tid >> 6] = q; }
  __syncthreads();
  s = rs[0] + rs[1] + rs[2] + rs[3];
  q = rq[0] + rq[1] + rq[2] + rq[3];
  float mean = s * (1.f / 1024.f);
  float var = q * (1.f / 1024.f) - mean * mean;
  float rstd = rsqrtf(var + 1e-5f);
  float4 g = *(const float4*)(sc + c);
  float4 bb = *(const float4*)(bi + c);
  bf16x4 o4;
  o4.x = f2bf((v.x - mean) * rstd * g.x + bb.x);
  o4.y = f2bf((v.y - mean) * rstd * g.y + bb.y);
  o4.z = f2bf((v.z - mean) * rstd * g.z + bb.z);
  o4.w = f2bf((v.w - mean) * rstd * g.w + bb.w);
  *(bf16x4*)(out + (size_t)row * 1024 + c) = o4;
}

// ------ lnred4: x += 4 partials + gbias; LN(x) -> h  (bf16 partials) ------
__global__ __launch_bounds__(256) void lnred4_kernel(float* __restrict__ xio,
                                                     const short* __restrict__ P01,
                                                     const short* __restrict__ P23,
                                                     const float* __restrict__ gb,
                                                     const float* __restrict__ sc,
                                                     const float* __restrict__ bi,
                                                     short* __restrict__ out) {
  const size_t MN = (size_t)M_ROWS * 1024;
  int row = blockIdx.x, tid = threadIdx.x;
  int c = tid << 2;
  size_t base = (size_t)row * 1024 + c;
  float4 v = *(const float4*)(xio + base);
  bf16x4 p0 = *(const bf16x4*)(P01 + base);
  bf16x4 p1 = *(const bf16x4*)(P01 + MN + base);
  bf16x4 p2 = *(const bf16x4*)(P23 + base);
  bf16x4 p3 = *(const bf16x4*)(P23 + MN + base);
  float4 gv = *(const float4*)(gb + c);
  v.x += bf2f(p0.x) + bf2f(p1.x) + bf2f(p2.x) + bf2f(p3.x) + gv.x;
  v.y += bf2f(p0.y) + bf2f(p1.y) + bf2f(p2.y) + bf2f(p3.y) + gv.y;
  v.z += bf2f(p0.z) + bf2f(p1.z) + bf2f(p2.z) + bf2f(p3.z) + gv.z;
  v.w += bf2f(p0.w) + bf2f(p1.w) + bf2f(p2.w) + bf2f(p3.w) + gv.w;
  *(float4*)(xio + base) = v;
  float s = v.x + v.y + v.z + v.w;
  float q = v.x * v.x + v.y * v.y + v.z * v.z + v.w * v.w;
#pragma unroll
  for (int off = 32; off > 0; off >>= 1) {
    s += __shfl_xor(s, off);
    q += __shfl_xor(q, off);
  }
  __shared__ float rs[4], rq[4];
  if ((tid & 63) == 0) { rs[tid >> 6] = s; rq[tid >> 6] = q; }
  __syncthreads();
  s = rs[0] + rs[1] + rs[2] + rs[3];
  q = rq[0] + rq[1] + rq[2] + rq[3];
  float mean = s * (1.f / 1024.f);
  float var = q * (1.f / 1024.f) - mean * mean;
  float rstd = rsqrtf(var + 1e-5f);
  float4 g = *(const float4*)(sc + c);
  float4 bb = *(const float4*)(bi + c);
  bf16x4 o4;
  o4.x = f2bf((v.x - mean) * rstd * g.x + bb.x);
  o4.y = f2bf((v.y - mean) * rstd * g.y + bb.y);
  o4.z = f2bf((v.z - mean) * rstd * g.z + bb.z);
  o4.w = f2bf((v.w - mean) * rstd * g.w + bb.w);
  *(bf16x4*)(out + (size_t)row * 1024 + c) = o4;
}

// ------ GEMM3SK: 64x128 tile, BK=64, split-K=2, 3-buf never-drain; bf16 partials ------
__global__ __launch_bounds__(256) void gemm3sk_kernel(const short* __restrict__ A,
                                                      const short* __restrict__ Bt,
                                                      short* __restrict__ Pout,
                                                      int K, int N) {
  constexpr int ABY = 64 * 128;
  constexpr int BBY = 128 * 128;
  extern __shared__ char smem[];
  char* Asm = smem;
  char* Bsm = smem + 3 * ABY;
  const int NB = N >> 7;
  int nwg = 64 * NB;
  int bid = blockIdx.x;
  int wgid = (bid & 7) * (nwg >> 3) + (bid >> 3);
  int half = wgid >= (nwg >> 1);
  int w2 = wgid - half * (nwg >> 1);
  int bn = w2 >> 5, bm = w2 & 31;
  int kbase = half * (K >> 1);
  Pout += (size_t)half * M_ROWS * N;
  int tid = threadIdx.x;
  int lane = tid & 63, w = tid >> 6;
  int lr = lane & 15, lg = lane >> 4;
  int wn = w & 1, wm = w >> 1;

  const floatx4 FZ = {0.f, 0.f, 0.f, 0.f};
  floatx4 acc[2][4];
#pragma unroll
  for (int m = 0; m < 2; ++m)
#pragma unroll
    for (int n = 0; n < 4; ++n) acc[m][n] = FZ;

  size_t aoff[2], boff[4];
  {
    int rr = tid >> 3;
    int g = (tid & 7) ^ (rr & 7);
#pragma unroll
    for (int i = 0; i < 2; ++i)
      aoff[i] = (size_t)(bm * 64 + i * 32 + rr) * K + kbase + g * 8;
#pragma unroll
    for (int i = 0; i < 4; ++i)
      boff[i] = (size_t)(bn * 128 + i * 32 + rr) * K + kbase + g * 8;
  }

#define STA3(b, k0)                                                        \
  _Pragma("unroll") for (int i = 0; i < 2; ++i)                            \
    lds_cp16(A + aoff[i] + (k0), Asm + (b) * ABY + i * 4096 + tid * 16);
#define STB3(b, k0)                                                        \
  _Pragma("unroll") for (int i = 0; i < 4; ++i)                            \
    lds_cp16(Bt + boff[i] + (k0), Bsm + (b) * BBY + i * 4096 + tid * 16);
#define LDA3(b, kh)                                                        \
  _Pragma("unroll") for (int f = 0; f < 2; ++f) {                          \
    int lrow = wm * 32 + f * 16 + lr;                                      \
    af[f] = *(const bf16x8*)(Asm + (b) * ABY + lrow * 128 +                \
                             (((((kh) << 2) + lg) ^ (lrow & 7)) << 4));    \
  }
#define LDB3(b, kh)                                                        \
  _Pragma("unroll") for (int n = 0; n < 4; ++n) {                          \
    int lcol = wn * 64 + n * 16 + lr;                                      \
    bfr[n] = *(const bf16x8*)(Bsm + (b) * BBY + lcol * 128 +               \
                              (((((kh) << 2) + lg) ^ (lcol & 7)) << 4));   \
  }
#define MFMA3                                                              \
  __builtin_amdgcn_s_setprio(1);                                           \
  _Pragma("unroll") for (int f = 0; f < 2; ++f)                            \
  _Pragma("unroll") for (int n = 0; n < 4; ++n)                            \
    acc[f][n] = __builtin_amdgcn_mfma_f32_16x16x32_bf16(af[f], bfr[n],     \
                                                        acc[f][n], 0, 0, 0);\
  __builtin_amdgcn_s_setprio(0);

  const int nt = (K >> 1) >> 6;
  STA3(0, 0); STB3(0, 0);
  STA3(1, 64); STB3(1, 64);
  WVM(6);
  BARR;

  int cbuf = 0, sbuf = 2;
  for (int t = 0; t < nt; ++t) {
    bf16x8 af[2], bfr[4];
    bool pre = (t + 2 < nt);
    int k2 = (t + 2) << 6;
    if (pre) { STA3(sbuf, k2); }
    LDA3(cbuf, 0); LDB3(cbuf, 0);
    MFMA3;
    if (pre) { STB3(sbuf, k2); }
    LDA3(cbuf, 1); LDB3(cbuf, 1);
    MFMA3;
    if (pre) { WVM(6); } else { WVM(0); }
    BARR;
    cbuf = (cbuf == 2) ? 0 : cbuf + 1;
    sbuf = (sbuf == 2) ? 0 : sbuf + 1;
  }

#pragma unroll
  for (int n = 0; n < 4; ++n) {
    int col = (bn << 7) + wn * 64 + (n << 4) + lr;
#pragma unroll
    for (int m = 0; m < 2; ++m) {
      int row0 = bm * 64 + wm * 32 + (m << 4) + (lg << 2);
#pragma unroll
      for (int r = 0; r < 4; ++r)
        Pout[(size_t)(row0 + r) * N + col] = f2bf(acc[m][n][r]);
    }
  }
#undef STA3
#undef STB3
#undef LDA3
#undef LDB3
#undef MFMA3
}

// ------ GEMMW: 128x256 tile, 8 waves (wave 64x64), 3-buf never-drain. 144KB LDS ------
// VSPLIT: cols >=2048 (QKV's V section) written transposed to vtb, skipped in Cout.
template <bool BIAS, bool RELU, bool OUTBF16, bool VSPLIT>
__global__ __launch_bounds__(512) void gemmw_kernel(const short* __restrict__ A,
                                                    const short* __restrict__ Bt,
                                                    const float* __restrict__ bias,
                                                    void* __restrict__ Cout,
                                                    short* __restrict__ vtb,
                                                    int K, int N) {
  constexpr int ABY = 128 * 128;   // 16KB per A buf
  constexpr int BBY = 256 * 128;   // 32KB per B buf
  extern __shared__ char smem[];
  char* Asm = smem;                // 3 bufs
  char* Bsm = smem + 3 * ABY;
  const int NB = N >> 8;
  int nwg = 16 * NB;
  int bid = blockIdx.x;
  int wgid = (bid & 7) * (nwg >> 3) + (bid >> 3);
  int bn = wgid >> 4, bm = wgid & 15;               // bn-major
  int tid = threadIdx.x;
  int lane = tid & 63, w = tid >> 6;
  int lr = lane & 15, lg = lane >> 4;
  int wm = w >> 2, wn = w & 3;

  const floatx4 FZ = {0.f, 0.f, 0.f, 0.f};
  floatx4 acc[4][4];
#pragma unroll
  for (int m = 0; m < 4; ++m)
#pragma unroll
    for (int n = 0; n < 4; ++n) acc[m][n] = FZ;

  size_t aoff[2], boff[4];
  {
    int rr = tid >> 3;                               // 0..63
    int g = (tid & 7) ^ (rr & 7);
#pragma unroll
    for (int i = 0; i < 2; ++i)
      aoff[i] = (size_t)(bm * 128 + i * 64 + rr) * K + g * 8;
#pragma unroll
    for (int i = 0; i < 4; ++i)
      boff[i] = (size_t)(bn * 256 + i * 64 + rr) * K + g * 8;
  }

#define STAW(b, k0)                                                        \
  _Pragma("unroll") for (int i = 0; i < 2; ++i)                            \
    lds_cp16(A + aoff[i] + (k0), Asm + (b) * ABY + i * 8192 + tid * 16);
#define STBW(b, k0)                                                        \
  _Pragma("unroll") for (int i = 0; i < 4; ++i)                            \
    lds_cp16(Bt + boff[i] + (k0), Bsm + (b) * BBY + i * 8192 + tid * 16);
#define LDAW(b, kh)                                                        \
  _Pragma("unroll") for (int f = 0; f < 4; ++f) {                          \
    int lrow = wm * 64 + f * 16 + lr;                                      \
    af[f] = *(const bf16x8*)(Asm + (b) * ABY + lrow * 128 +                \
                             (((((kh) << 2) + lg) ^ (lrow & 7)) << 4));    \
  }
#define LDBW(b, kh)                                                        \
  _Pragma("unroll") for (int n = 0; n < 4; ++n) {                          \
    int lcol = wn * 64 + n * 16 + lr;                                      \
    bfr[n] = *(const bf16x8*)(Bsm + (b) * BBY + lcol * 128 +               \
                              (((((kh) << 2) + lg) ^ (lcol & 7)) << 4));   \
  }
#define MFMAW                                                              \
  __builtin_amdgcn_s_setprio(1);                                           \
  _Pragma("unroll") for (int f = 0; f < 4; ++f)                            \
  _Pragma("unroll") for (int n = 0; n < 4; ++n)                            \
    acc[f][n] = __builtin_amdgcn_mfma_f32_16x16x32_bf16(af[f], bfr[n],     \
                                                        acc[f][n], 0, 0, 0);\
  __builtin_amdgcn_s_setprio(0);

  const int nt = K >> 6;
  STAW(0, 0); STBW(0, 0);
  STAW(1, 64); STBW(1, 64);
  WVM(6);
  BARR;

  int cbuf = 0, sbuf = 2;
  for (int t = 0; t < nt; ++t) {
    bf16x8 af[4], bfr[4];
    bool pre = (t + 2 < nt);
    int k2 = (t + 2) << 6;
    if (pre) { STAW(sbuf, k2); }
    LDAW(cbuf, 0); LDBW(cbuf, 0);
    MFMAW;
    if (pre) { STBW(sbuf, k2); }
    LDAW(cbuf, 1); LDBW(cbuf, 1);
    MFMAW;
    if (pre) { WVM(6); } else { WVM(0); }
    BARR;
    cbuf = (cbuf == 2) ? 0 : cbuf + 1;
    sbuf = (sbuf == 2) ? 0 : sbuf + 1;
  }

#pragma unroll
  for (int n = 0; n < 4; ++n) {
    int col = (bn << 8) + wn * 64 + (n << 4) + lr;
    float bv = 0.f;
    if (BIAS) bv = bias[col];
#pragma unroll
    for (int m = 0; m < 4; ++m) {
      int row0 = bm * 128 + wm * 64 + (m << 4) + (lg << 2);
      if (VSPLIT && col >= 2048) {
        int hc = col - 2048;
        int brow = row0 >> 10, t0 = row0 & 1023;
        ushort4 pk;
        pk.x = (unsigned short)f2bf(acc[m][n][0]);
        pk.y = (unsigned short)f2bf(acc[m][n][1]);
        pk.z = (unsigned short)f2bf(acc[m][n][2]);
        pk.w = (unsigned short)f2bf(acc[m][n][3]);
        *(ushort4*)(vtb + ((size_t)(((brow << 4) + (hc >> 6)) << 6) + (hc & 63)) * 1024 + t0) = pk;
      } else {
#pragma unroll
        for (int r = 0; r < 4; ++r) {
          size_t idx = (size_t)(row0 + r) * N + col;
          float val = acc[m][n][r] + bv;
          if (RELU) val = fmaxf(val, 0.f);
          if (OUTBF16) ((short*)Cout)[idx] = f2bf(val);
          else ((float*)Cout)[idx] = val;
        }
      }
    }
  }
#undef STAW
#undef STBW
#undef LDAW
#undef LDBW
#undef MFMAW
}

// ------ GEMMWSK: gemmw with split-K=4, bf16 partials (parts 0,1->P01; 2,3->P23) ------
__global__ __launch_bounds__(512) void gemmwsk_kernel(const short* __restrict__ A,
                                                      const short* __restrict__ Bt,
                                                      short* __restrict__ P01,
                                                      short* __restrict__ P23,
                                                      int K, int N) {
  constexpr int ABY = 128 * 128;
  constexpr int BBY = 256 * 128;
  extern __shared__ char smem[];
  char* Asm = smem;
  char* Bsm = smem + 3 * ABY;
  const int NB = N >> 8;
  int nwg = 16 * NB * 4;
  int bid = blockIdx.x;
  int wgid = (bid & 7) * (nwg >> 3) + (bid >> 3);
  int per = nwg >> 2;
  int part = wgid / per;
  int w2 = wgid - part * per;
  int bn = w2 >> 4, bm = w2 & 15;
  int kbase = part * (K >> 2);
  short* Pout = (part < 2 ? P01 + (size_t)part * M_ROWS * N
                          : P23 + (size_t)(part - 2) * M_ROWS * N);
  int tid = threadIdx.x;
  int lane = tid & 63, w = tid >> 6;
  int lr = lane & 15, lg = lane >> 4;
  int wm = w >> 2, wn = w & 3;

  const floatx4 FZ = {0.f, 0.f, 0.f, 0.f};
  floatx4 acc[4][4];
#pragma unroll
  for (int m = 0; m < 4; ++m)
#pragma unroll
    for (int n = 0; n < 4; ++n) acc[m][n] = FZ;

  size_t aoff[2], boff[4];
  {
    int rr = tid >> 3;
    int g = (tid & 7) ^ (rr & 7);
#pragma unroll
    for (int i = 0; i < 2; ++i)
      aoff[i] = (size_t)(bm * 128 + i * 64 + rr) * K + kbase + g * 8;
#pragma unroll
    for (int i = 0; i < 4; ++i)
      boff[i] = (size_t)(bn * 256 + i * 64 + rr) * K + kbase + g * 8;
  }

#define STAW(b, k0)                                                        \
  _Pragma("unroll") for (int i = 0; i < 2; ++i)                            \
    lds_cp16(A + aoff[i] + (k0), Asm + (b) * ABY + i * 8192 + tid * 16);
#define STBW(b, k0)                                                        \
  _Pragma("unroll") for (int i = 0; i < 4; ++i)                            \
    lds_cp16(Bt + boff[i] + (k0), Bsm + (b) * BBY + i * 8192 + tid * 16);
#define LDAW(b, kh)                                                        \
  _Pragma("unroll") for (int f = 0; f < 4; ++f) {                          \
    int lrow = wm * 64 + f * 16 + lr;                                      \
    af[f] = *(const bf16x8*)(Asm + (b) * ABY + lrow * 128 +                \
                             (((((kh) << 2) + lg) ^ (lrow & 7)) << 4));    \
  }
#define LDBW(b, kh)                                                        \
  _Pragma("unroll") for (int n = 0; n < 4; ++n) {                          \
    int lcol = wn * 64 + n * 16 + lr;                                      \
    bfr[n] = *(const bf16x8*)(Bsm + (b) * BBY + lcol * 128 +               \
                              (((((kh) << 2) + lg) ^ (lcol & 7)) << 4));   \
  }
#define MFMAW                                                              \
  __builtin_amdgcn_s_setprio(1);                                           \
  _Pragma("unroll") for (int f = 0; f < 4; ++f)                            \
  _Pragma("unroll") for (int n = 0; n < 4; ++n)                            \
    acc[f][n] = __builtin_amdgcn_mfma_f32_16x16x32_bf16(af[f], bfr[n],     \
                                                        acc[f][n], 0, 0, 0);\
  __builtin_amdgcn_s_setprio(0);

  const int nt = (K >> 2) >> 6;
  STAW(0, 0); STBW(0, 0);
  STAW(1, 64); STBW(1, 64);
  WVM(6);
  BARR;

  int cbuf = 0, sbuf = 2;
  for (int t = 0; t < nt; ++t) {
    bf16x8 af[4], bfr[4];
    bool pre = (t + 2 < nt);
    int k2 = (t + 2) << 6;
    if (pre) { STAW(sbuf, k2); }
    LDAW(cbuf, 0); LDBW(cbuf, 0);
    MFMAW;
    if (pre) { STBW(sbuf, k2); }
    LDAW(cbuf, 1); LDBW(cbuf, 1);
    MFMAW;
    if (pre) { WVM(6); } else { WVM(0); }
    BARR;
    cbuf = (cbuf == 2) ? 0 : cbuf + 1;
    sbuf = (sbuf == 2) ? 0 : sbuf + 1;
  }

#pragma unroll
  for (int n = 0; n < 4; ++n) {
    int col = (bn << 8) + wn * 64 + (n << 4) + lr;
#pragma unroll
    for (int m = 0; m < 4; ++m) {
      int row0 = bm * 128 + wm * 64 + (m << 4) + (lg << 2);
#pragma unroll
      for (int r = 0; r < 4; ++r)
        Pout[(size_t)(row0 + r) * N + col] = f2bf(acc[m][n][r]);
    }
  }
#undef STAW
#undef STBW
#undef LDAW
#undef LDBW
#undef MFMAW
}

// ---------------- GEMM8: 256x256 8-phase, dynamic LDS 128KB (LM head) ----------------
template <bool BIAS, bool OUTBF16>
__global__ __launch_bounds__(512) void gemm8_kernel(const short* __restrict__ A,
                                                    const short* __restrict__ Bt,
                                                    const float* __restrict__ bias,
                                                    void* __restrict__ Cout,
                                                    int K, int N) {
  extern __shared__ char smem[];
  char* Asm = smem;            // [buf][chunk][128 rows][128B]
  char* Bsm = smem + 65536;    // [buf][256 cols][128B]
  const int NB = N >> 8;
  int nwg = 8 * NB;
  int bid = blockIdx.x;
  int wgid = (bid & 7) * (nwg >> 3) + (bid >> 3);
  int bm = wgid & 7, bn = wgid >> 3;
  int tid = threadIdx.x;
  int lane = tid & 63, w = tid >> 6;
  int lr = lane & 15, lg = lane >> 4;
  int wm = w >> 2, wn = w & 3;

  const floatx4 FZ = {0.f, 0.f, 0.f, 0.f};
  floatx4 acc[8][4];
#pragma unroll
  for (int m = 0; m < 8; ++m)
#pragma unroll
    for (int n = 0; n < 4; ++n) acc[m][n] = FZ;

  size_t aoff[2][2], boff[4];
  {
    int rr = tid >> 3;
    int g = (tid & 7) ^ (rr & 7);
#pragma unroll
    for (int c = 0; c < 2; ++c)
#pragma unroll
      for (int i = 0; i < 2; ++i) {
        int lrow = i * 64 + rr;
        int grow = (lrow & 63) + ((lrow >> 6) << 7) + (c << 6);
        aoff[c][i] = (size_t)(bm * 256 + grow) * K + g * 8;
      }
#pragma unroll
    for (int i = 0; i < 4; ++i)
      boff[i] = (size_t)(bn * 256 + i * 64 + rr) * K + g * 8;
  }

  bf16x8 areg[4], breg[2][4];

#define LDA8(chunk, kh)                                                          \
  _Pragma("unroll") for (int f = 0; f < 4; ++f) {                                \
    int lrow = wm * 64 + f * 16 + lr;                                            \
    areg[f] = *(const bf16x8*)(Asm + buf * 32768 + (chunk) * 16384 + lrow * 128  \
                               + (((((kh) << 2) + lg) ^ (lrow & 7)) << 4));      \
  }
#define LDB8(kh)                                                                 \
  _Pragma("unroll") for (int n = 0; n < 4; ++n) {                                \
    int lcol = wn * 64 + n * 16 + lr;                                            \
    breg[kh][n] = *(const bf16x8*)(Bsm + buf * 32768 + lcol * 128                \
                                   + (((((kh) << 2) + lg) ^ (lcol & 7)) << 4));  \
  }
#define MFMA16(mh, kh)                                                           \
  __builtin_amdgcn_s_setprio(1);                                                 \
  _Pragma("unroll") for (int f = 0; f < 4; ++f)                                  \
  _Pragma("unroll") for (int n = 0; n < 4; ++n)                                  \
    acc[(mh) * 4 + f][n] = __builtin_amdgcn_mfma_f32_16x16x32_bf16(              \
        areg[f], breg[kh][n], acc[(mh) * 4 + f][n], 0, 0, 0);                    \
  __builtin_amdgcn_s_setprio(0);
#define STA8(chunk, dstbuf, k0)                                                  \
  _Pragma("unroll") for (int i = 0; i < 2; ++i)                                  \
    lds_cp16(A + aoff[chunk][i] + (k0),                                          \
             Asm + (dstbuf) * 32768 + (chunk) * 16384 + i * 8192 + tid * 16);
#define STB8(dstbuf, k0)                                                         \
  _Pragma("unroll") for (int i = 0; i < 4; ++i)                                  \
    lds_cp16(Bt + boff[i] + (k0),                                                \
             Bsm + (dstbuf) * 32768 + i * 8192 + tid * 16);

  const int nt = K >> 6;
  STA8(0, 0, 0); STB8(0, 0); STA8(1, 0, 0);
  WVM(2);
  BARR;

  int buf = 0;
  for (int t = 0; t < nt - 1; ++t) {
    int k1 = (t + 1) << 6;
    int ob = buf ^ 1;
    LDA8(0, 0); LDB8(0);
    STA8(0, ob, k1);
    BARR;
    MFMA16(0, 0);
    BARR;
    LDA8(0, 1); LDB8(1);
    STB8(ob, k1);
    WVM(6);
    BARR;
    MFMA16(0, 1);
    BARR;
    LDA8(1, 0);
    STA8(1, ob, k1);
    BARR;
    MFMA16(1, 0);
    BARR;
    LDA8(1, 1);
    WVM(2);
    BARR;
    MFMA16(1, 1);
    BARR;
    buf ^= 1;
  }
  LDA8(0, 0); LDB8(0);
  MFMA16(0, 0);
  LDA8(0, 1); LDB8(1);
  MFMA16(0, 1);
  WVM(0);
  BARR;
  LDA8(1, 0);
  MFMA16(1, 0);
  LDA8(1, 1);
  MFMA16(1, 1);

#pragma unroll
  for (int n = 0; n < 4; ++n) {
    int col = (bn << 8) + (wn << 6) + (n << 4) + lr;
    float bv = 0.f;
    if (BIAS) bv = bias[col];
#pragma unroll
    for (int m = 0; m < 8; ++m) {
      int row0 = (bm << 8) + (wm << 7) + (m << 4) + (lg << 2);
#pragma unroll
      for (int r = 0; r < 4; ++r) {
        size_t idx = (size_t)(row0 + r) * N + col;
        float val = acc[m][n][r] + bv;
        if (OUTBF16) ((short*)Cout)[idx] = f2bf(val);
        else ((float*)Cout)[idx] = val;
      }
    }
  }
#undef LDA8
#undef LDB8
#undef MFMA16
#undef STA8
#undef STB8
}

// -------- flash attention: KVBLK=128, causal load-balanced (whole + kv-split halves) --------
// grid (32 bh, 24): y<8 -> whole q-tile qt=y; y>=8 -> qt=8+(y-8)/2, half=(y-8)&1.
// Halves emit unnormalized partials (o f32, m, l) for attnmerge.
__global__ __launch_bounds__(256) void attn_kernel(const short* __restrict__ qkv,
                                                   const short* __restrict__ vt,
                                                   short* __restrict__ out,
                                                   float* __restrict__ po,
                                                   float* __restrict__ pm,
                                                   float* __restrict__ pl) {
  int bh = blockIdx.x;
  int y = blockIdx.y;
  int qt, c0, cend, half = 0;
  bool whole, epi;
  if (y < 8) {
    qt = y; whole = true; c0 = 0; cend = qt >> 1; epi = true;
  } else {
    int idx = y - 8;
    qt = 8 + (idx >> 1); half = idx & 1; whole = false;
    int nfull = qt >> 1;            // = nc-1
    int h0 = (nfull + 1) >> 1;      // nc>>1
    if (half == 0) { c0 = 0; cend = h0; epi = false; }
    else           { c0 = h0; cend = nfull; epi = true; }
  }
  int b = bh >> 4, hh = bh & 15;
  int tid = threadIdx.x;
  int lane = tid & 63, w = tid >> 6;
  int lr = lane & 15, lg = lane >> 4;

  __shared__ short Ks[128 * 64];    // [kv][hs], 128B rows, granule ^= row&7
  __shared__ short Vs[64 * 128];    // V^T [hs][kv], 256B rows, granule ^= row&15
  __shared__ short Ps[4][16 * 132]; // per-wave P strip

  const floatx4 FZ = {0.f, 0.f, 0.f, 0.f};
  const float C2 = 0.18033688f;     // HS^-0.5 * log2(e)
  const short* qb = qkv + (size_t)((b << 10) + (qt << 6) + (w << 4) + lr) * 3072 + (hh << 6);
  bf16x8 qf0 = *(const bf16x8*)(qb + (lg << 3));
  bf16x8 qf1 = *(const bf16x8*)(qb + 32 + (lg << 3));

  floatx4 o[4];
  float mrun[4], lrun[4];
#pragma unroll
  for (int r = 0; r < 4; ++r) { o[r] = FZ; mrun[r] = -3e38f; lrun[r] = 0.f; }

  int krow = tid >> 3, kgr = tid & 7;
  int vrow = tid >> 4, vgr = tid & 15;
  const short* kB = qkv + (size_t)(b << 10) * 3072 + 1024 + (hh << 6);
  const short* vB = vt + (size_t)(bh << 6) * 1024;

#define STKV(JT)                                                           \
  _Pragma("unroll") for (int i = 0; i < 4; ++i) {                          \
    int r = (i << 5) + krow;                                               \
    lds_cp16(kB + (size_t)(((JT) << 7) + r) * 3072 + ((kgr ^ (r & 7)) << 3), \
             (char*)Ks + i * 4096 + tid * 16);                             \
  }                                                                        \
  _Pragma("unroll") for (int i = 0; i < 4; ++i) {                          \
    int r = (i << 4) + vrow;                                               \
    lds_cp16(vB + (size_t)r * 1024 + ((JT) << 7) + ((vgr ^ (r & 15)) << 3), \
             (char*)Vs + i * 4096 + tid * 16);                             \
  }

#define CHUNK_COMPUTE(NF, MASK, JT)                                        \
  {                                                                        \
    const char* KsB = (const char*)Ks;                                     \
    const char* VsB = (const char*)Vs;                                     \
    floatx4 s[NF];                                                         \
    _Pragma("unroll") for (int f = 0; f < NF; ++f) {                       \
      int rk = (f << 4) + lr;                                              \
      int sw = rk & 7;                                                     \
      bf16x8 kf0 = *(const bf16x8*)(KsB + rk * 128 + ((lg ^ sw) << 4));    \
      bf16x8 kf1 = *(const bf16x8*)(KsB + rk * 128 + (((4 + lg) ^ sw) << 4)); \
      floatx4 t0 = __builtin_amdgcn_mfma_f32_16x16x32_bf16(qf0, kf0, FZ, 0, 0, 0); \
      s[f] = __builtin_amdgcn_mfma_f32_16x16x32_bf16(qf1, kf1, t0, 0, 0, 0); \
    }                                                                      \
    int qrow0 = (qt << 6) + (w << 4) + (lg << 2);                          \
    _Pragma("unroll") for (int f = 0; f < NF; ++f)                         \
    _Pragma("unroll") for (int r = 0; r < 4; ++r) {                        \
      float sv = s[f][r] * C2;                                             \
      if (MASK && (((JT) << 7) + (f << 4) + lr > qrow0 + r)) sv = -3e38f;  \
      s[f][r] = sv;                                                        \
    }                                                                      \
    float mt[4] = {-3e38f, -3e38f, -3e38f, -3e38f};                        \
    _Pragma("unroll") for (int f = 0; f < NF; ++f)                         \
    _Pragma("unroll") for (int r = 0; r < 4; ++r) mt[r] = fmaxf(mt[r], s[f][r]); \
    _Pragma("unroll") for (int off = 1; off < 16; off <<= 1)               \
    _Pragma("unroll") for (int r = 0; r < 4; ++r)                          \
      mt[r] = fmaxf(mt[r], __shfl_xor(mt[r], off));                        \
    float corr[4], psum[4];                                                \
    _Pragma("unroll") for (int r = 0; r < 4; ++r) {                        \
      float mnew = fmaxf(mrun[r], mt[r]);                                  \
      corr[r] = exp2f(mrun[r] - mnew);                                     \
      mrun[r] = mnew;                                                      \
      float ps = 0.f;                                                      \
      _Pragma("unroll") for (int f = 0; f < NF; ++f) {                     \
        float e = exp2f(s[f][r] - mnew);                                   \
        s[f][r] = e;                                                       \
        ps += e;                                                           \
      }                                                                    \
      psum[r] = ps;                                                        \
    }                                                                      \
    _Pragma("unroll") for (int off = 1; off < 16; off <<= 1)               \
    _Pragma("unroll") for (int r = 0; r < 4; ++r)                          \
      psum[r] += __shfl_xor(psum[r], off);                                 \
    floatx4 cv;                                                            \
    _Pragma("unroll") for (int r = 0; r < 4; ++r) {                        \
      lrun[r] = lrun[r] * corr[r] + psum[r];                               \
      cv[r] = corr[r];                                                     \
    }                                                                      \
    _Pragma("unroll") for (int f = 0; f < 4; ++f) o[f] *= cv;              \
    char* PsB = (char*)&Ps[w][0];                                          \
    _Pragma("unroll") for (int f = 0; f < NF; ++f)                         \
    _Pragma("unroll") for (int r = 0; r < 4; ++r)                          \
      *(short*)(PsB + ((lg << 2) + r) * 264 + (((f << 4) + lr) << 1)) =    \
          f2bf(s[f][r]);                                                   \
    _Pragma("unroll") for (int kk = 0; kk < (NF >> 1); ++kk) {             \
      const char* pb = PsB + lr * 264 + (kk << 6) + (lg << 4);             \
      union { struct { bf16x4 lo, hi; } h2; bf16x8 v; } pu;                \
      pu.h2.lo = *(const bf16x4*)pb;                                       \
      pu.h2.hi = *(const bf16x4*)(pb + 8);                                 \
      bf16x8 pa = pu.v;                                                    \
      _Pragma("unroll") for (int f = 0; f < 4; ++f) {                      \
        int rv = (f << 4) + lr;                                            \
        bf16x8 vf = *(const bf16x8*)(VsB + rv * 256 +                      \
                                     ((((kk << 2) + lg) ^ (rv & 15)) << 4)); \
        o[f] = __builtin_amdgcn_mfma_f32_16x16x32_bf16(pa, vf, o[f], 0, 0, 0); \
      }                                                                    \
    }                                                                      \
  }

  for (int jt = c0; jt < cend; ++jt) {
    STKV(jt);
    WVM(0);
    BARR;
    CHUNK_COMPUTE(8, false, jt)
    BARR;
  }
  if (epi) {
    int je = qt >> 1;
    STKV(je);
    WVM(0);
    BARR;
    if (qt & 1) {
      CHUNK_COMPUTE(8, true, je)
    } else {
      CHUNK_COMPUTE(4, true, je)
    }
  }
#undef STKV
#undef CHUNK_COMPUTE

  if (whole) {
#pragma unroll
    for (int f = 0; f < 4; ++f) {
#pragma unroll
      for (int r = 0; r < 4; ++r) {
        int row = (qt << 6) + (w << 4) + (lg << 2) + r;
        int col = (hh << 6) + (f << 4) + lr;
        out[(size_t)((b << 10) + row) * 1024 + col] = f2bf(o[f][r] / lrun[r]);
      }
    }
  } else {
    int qtp = qt - 8;
    size_t pb = (((size_t)bh * 8 + qtp) * 2 + half) << 12;   // *4096
#pragma unroll
    for (int f = 0; f < 4; ++f) {
#pragma unroll
      for (int r = 0; r < 4; ++r) {
        int row = (w << 4) + (lg << 2) + r;
        int col = (f << 4) + lr;
        po[pb + row * 64 + col] = o[f][r];
      }
    }
    if (lr == 0) {
      int mi = (int)((((bh * 8 + qtp) << 1) + half) << 6);
#pragma unroll
      for (int r = 0; r < 4; ++r) {
        int row = (w << 4) + (lg << 2) + r;
        pm[mi + row] = mrun[r];
        pl[mi + row] = lrun[r];
      }
    }
  }
}

// ---- attnmerge: combine two kv-half partials per (bh, qt>=8), exact LSE merge ----
__global__ __launch_bounds__(256) void attnmerge_kernel(const float* __restrict__ po,
                                                        const float* __restrict__ pm,
                                                        const float* __restrict__ pl,
                                                        short* __restrict__ out) {
  int bh = blockIdx.x, y = blockIdx.y;
  int qt = 8 + y;
  int b = bh >> 4, hh = bh & 15;
  int tid = threadIdx.x;
  int row = tid >> 2, cg = tid & 3;
  size_t base0 = ((((size_t)bh * 8 + y) * 2) << 12) + row * 64;
  size_t base1 = base0 + 4096;
  int mi = (((bh * 8 + y) << 1) << 6) + row;
  float m0 = pm[mi], l0 = pl[mi];
  float m1 = pm[mi + 64], l1 = pl[mi + 64];
  float M = fmaxf(m0, m1);
  float w0 = exp2f(m0 - M), w1 = exp2f(m1 - M);
  float inv = 1.f / (l0 * w0 + l1 * w1);
  short* op = out + (size_t)((b << 10) + (qt << 6) + row) * 1024 + (hh << 6) + (cg << 4);
#pragma unroll
  for (int p = 0; p < 4; ++p) {
    float4 a = *(const float4*)(po + base0 + (cg << 4) + (p << 2));
    float4 c = *(const float4*)(po + base1 + (cg << 4) + (p << 2));
    bf16x4 o4;
    o4.x = f2bf((a.x * w0 + c.x * w1) * inv);
    o4.y = f2bf((a.y * w0 + c.y * w1) * inv);
    o4.z = f2bf((a.z * w0 + c.z * w1) * inv);
    o4.w = f2bf((a.w * w0 + c.w * w1) * inv);
    *(bf16x4*)(op + (p << 2)) = o4;
  }
}

// ---------------- launch ----------------
extern "C" void kernel_launch(void* const* d_in, const int* in_sizes, int n_in,
                              void* d_out, int out_size, void* d_ws, size_t ws_size,
                              hipStream_t stream) {
  const int*   tokens  = (const int*)d_in[0];
  const float* tok_emb = (const float*)d_in[1];
  const float* pos_emb = (const float*)d_in[2];
  const float* Wq  = (const float*)d_in[3];
  const float* Wk  = (const float*)d_in[4];
  const float* Wv  = (const float*)d_in[5];
  const float* Wo  = (const float*)d_in[6];
  const float* bo  = (const float*)d_in[7];
  const float* ln1s = (const float*)d_in[8];
  const float* ln1b = (const float*)d_in[9];
  const float* ln2s = (const float*)d_in[10];
  const float* ln2b = (const float*)d_in[11];
  const float* W1  = (const float*)d_in[12];
  const float* b1  = (const float*)d_in[13];
  const float* W2  = (const float*)d_in[14];
  const float* b2  = (const float*)d_in[15];
  const float* lnfs = (const float*)d_in[16];
  const float* lnfb = (const float*)d_in[17];
  const float* Wlm = (const float*)d_in[18];
  const float* blm = (const float*)d_in[19];

  short* wqkvT = (short*)d_ws;                               // [L][3072][1024]
  short* woT   = wqkvT + (size_t)L_LAYERS * 3072 * 1024;     // [L][1024][1024]
  short* w1T   = woT   + (size_t)L_LAYERS * 1024 * 1024;     // [L][4096][1024]
  short* w2T   = w1T   + (size_t)L_LAYERS * 4096 * 1024;     // [L][1024][4096]
  short* wlmT  = w2T   + (size_t)L_LAYERS * 1024 * 4096;     // [32000][1024]
  float* x     = (float*)(wlmT + (size_t)V_VOCAB * 1024);    // [2048][1024] f32
  short* h     = (short*)(x + (size_t)M_ROWS * 1024);        // [2048][1024] bf16
  short* qkv   = h + (size_t)M_ROWS * 1024;                  // [2048][3072] bf16
  short* vtb   = qkv + (size_t)M_ROWS * 3072;                // [32][64][1024] bf16
  short* attnb = vtb + (size_t)B_BATCH * N_HEAD * H_SZ * T_SEQ; // [2048][1024]
  short* mid   = attnb + (size_t)M_ROWS * 1024;              // [2048][4096] bf16
  short* psum  = mid + (size_t)M_ROWS * 4096;                // 2x[2048][1024] bf16
  short* psum1 = psum + (size_t)M_ROWS * 1024;
  // split-K parts 2,3 reuse the dead qkv+vtb region
  short* psum23 = qkv;
  // attn partials live in mid (dead during attn): o 8.4MB + m/l 256KB < 16MB
  float* apo = (float*)mid;                                  // [32][8][2][64][64] f32
  float* apm = apo + (size_t)32 * 8 * 2 * 64 * 64;           // [32][8][2][64]
  float* apl = apm + 32 * 8 * 2 * 64;

  dim3 blk(256, 1, 1);

  // raise dynamic-LDS caps (idempotent, host-side, capture-safe)
  (void)hipFuncSetAttribute(reinterpret_cast<const void*>(&gemm8_kernel<true, false>),
                            hipFuncAttributeMaxDynamicSharedMemorySize, 131072);
  (void)hipFuncSetAttribute(reinterpret_cast<const void*>(&gemm3sk_kernel),
                            hipFuncAttributeMaxDynamicSharedMemorySize, 73728);
  (void)hipFuncSetAttribute(reinterpret_cast<const void*>(&gemmw_kernel<false, false, true, true>),
                            hipFuncAttributeMaxDynamicSharedMemorySize, 147456);
  (void)hipFuncSetAttribute(reinterpret_cast<const void*>(&gemmw_kernel<true, true, true, false>),
                            hipFuncAttributeMaxDynamicSharedMemorySize, 147456);
  (void)hipFuncSetAttribute(reinterpret_cast<const void*>(&gemmwsk_kernel),
                            hipFuncAttributeMaxDynamicSharedMemorySize, 147456);

  // ---- weight prep ----
  transpose_cvt<<<dim3(16, 16, 6), blk, 0, stream>>>(Wq, wqkvT,             1024, 1024, 1048576, 3072 * 1024);
  transpose_cvt<<<dim3(16, 16, 6), blk, 0, stream>>>(Wk, wqkvT + 1048576,   1024, 1024, 1048576, 3072 * 1024);
  transpose_cvt<<<dim3(16, 16, 6), blk, 0, stream>>>(Wv, wqkvT + 2097152,   1024, 1024, 1048576, 3072 * 1024);
  transpose_cvt<<<dim3(16, 16, 6), blk, 0, stream>>>(Wo, woT,               1024, 1024, 1048576, 1048576);
  transpose_cvt<<<dim3(16, 64, 6), blk, 0, stream>>>(W1, w1T,               1024, 4096, 4194304, 4194304);
  transpose_cvt<<<dim3(64, 16, 6), blk, 0, stream>>>(W2, w2T,               4096, 1024, 4194304, 4194304);
  transpose_cvt<<<dim3(16, 500, 1), blk, 0, stream>>>(Wlm, wlmT,            1024, V_VOCAB, 0, 0);

  // ---- forward ----
  embedln_kernel<<<M_ROWS, blk, 0, stream>>>(tokens, tok_emb, pos_emb, x, ln1s, ln1b, h);

  for (int l = 0; l < L_LAYERS; ++l) {
    if (l > 0) {
      lnred4_kernel<<<M_ROWS, blk, 0, stream>>>(x, psum, psum23, b2 + (l - 1) * 1024,
                                                ln1s + l * 1024, ln1b + l * 1024, h);
    }
    // QKV: 128x256-tile 8-wave; V section written transposed to vtb (VSPLIT)
    gemmw_kernel<false, false, true, true><<<16 * 12, dim3(512, 1, 1), 147456, stream>>>(
        h, wqkvT + (size_t)l * 3072 * 1024, nullptr, qkv, vtb, 1024, 3072);
    // attn: load-balanced (whole qt<8 + kv-split halves for qt>=8) + merge
    attn_kernel<<<dim3(32, 24), blk, 0, stream>>>(qkv, vtb, attnb, apo, apm, apl);
    attnmerge_kernel<<<dim3(32, 8), blk, 0, stream>>>(apo, apm, apl, attnb);
    // proj split-K=2 -> bf16 partials (512 blocks, nt=8)
    gemm3sk_kernel<<<64 * 8, blk, 73728, stream>>>(
        attnb, woT + (size_t)l * 1048576, psum, 1024, 1024);
    lnred_kernel<<<M_ROWS, blk, 0, stream>>>(x, psum, psum1, bo + l * 1024,
                                             ln2s + l * 1024, ln2b + l * 1024, h);
    // MLP1: 128x256-tile 8-wave (grid 256)
    gemmw_kernel<true, true, true, false><<<16 * 16, dim3(512, 1, 1), 147456, stream>>>(
        h, w1T + (size_t)l * 4194304, b1 + l * 4096, mid, nullptr, 1024, 4096);
    // MLP2 split-K=4 -> bf16 partials (parts 2,3 over dead qkv buffer; nt=16)
    gemmwsk_kernel<<<16 * 16, dim3(512, 1, 1), 147456, stream>>>(
        mid, w2T + (size_t)l * 4194304, psum, psum23, 4096, 1024);
  }

  lnred4_kernel<<<M_ROWS, blk, 0, stream>>>(x, psum, psum23, b2 + 5 * 1024,
                                            lnfs, lnfb, h);
  gemm8_kernel<true, false><<<dim3(8 * 125), dim3(512, 1, 1), 131072, stream>>>(
      h, wlmT, blm, (float*)d_out, 1024, V_VOCAB);
}